// Round 14
// baseline (148.312 us; speedup 1.0000x reference)
//
#include <hip/hip_runtime.h>
#include <hip/hip_bf16.h>
#include <stdint.h>

// ESPNET MultiHeadedAttention: T=2048 B=2 F=1024 H=16 DK=64
// prep(w-cvt+mask) -> QKV proj GEMM (2-barrier, XCD grid, BOTH operands
// register-prefetched one K-step ahead -> barrier-to-barrier section is
// ds_write-only; Q pre-scaled, masked K/V rows zeroed) -> flash attn
// (mask-free, unroll-2 pairs, swapped QK^T, static-max softmax, ones-MFMA
// row-sums, tr_b16 V, XCD grid) -> out GEMM (gload16 2-barrier, fp32 out)

typedef __bf16 bf16_t;
typedef __bf16 bf16x4 __attribute__((ext_vector_type(4)));
typedef __bf16 bf16x8 __attribute__((ext_vector_type(8)));
typedef float f32x4 __attribute__((ext_vector_type(4)));
typedef unsigned int u32x2 __attribute__((ext_vector_type(2)));

typedef const __attribute__((address_space(1))) void* gas_ptr;
typedef __attribute__((address_space(3))) void* las_ptr;

__device__ __forceinline__ void gload16(const void* g, void* lds) {
    // async global->LDS, 16B/lane; LDS dest = wave-uniform base + lane*16
    __builtin_amdgcn_global_load_lds((gas_ptr)g, (las_ptr)lds, 16, 0, 0);
}

// XOR swizzle for 128-B-row tiles: involution, moves 16B blocks, stays in-row
__device__ __forceinline__ int swz(int o) { return o ^ (((o >> 7) & 7) << 4); }

// V staging pre-permutation: 16B chunk c of subtiled LDS [key/4][d/16][4][16]
// comes from global byte offset (key*128 + d*2) of the 64x64 V tile.
__device__ __forceinline__ int gofs(int c) {
    return ((c >> 5) << 9) + (((c >> 1) & 3) << 7) + (((c >> 3) & 3) << 5) + ((c & 1) << 4);
}

#define TRREAD(dst, addr, IMM) \
    asm volatile("ds_read_b64_tr_b16 %0, %1 offset:" #IMM : "=v"(dst) : "v"(addr))

#if __has_builtin(__builtin_amdgcn_exp2f)
#define EXP2F(x) __builtin_amdgcn_exp2f(x)
#else
#define EXP2F(x) exp2f(x)
#endif
#if __has_builtin(__builtin_amdgcn_rcpf)
#define RCPF(x) __builtin_amdgcn_rcpf(x)
#else
#define RCPF(x) (1.0f / (x))
#endif

// ---------------- prep: cvt w4 + mask bits ----------------------------------
__global__ __launch_bounds__(256) void prep_all_kernel(const float* __restrict__ wq,
                                                       const float* __restrict__ wk,
                                                       const float* __restrict__ wv,
                                                       const float* __restrict__ wo,
                                                       const unsigned char* __restrict__ mraw,
                                                       bf16_t* __restrict__ wdst,
                                                       unsigned long long* __restrict__ mbits) {
    const int bidx = blockIdx.x;
    const int tid = threadIdx.x;
    if (bidx < 2048) {
        // fp32 -> bf16, 4 weight matrices (contiguous dst)
        int idx = bidx * 256 + tid;
        int which = idx >> 17;               // 131072 threads per matrix
        int loc = idx & 131071;
        const float* src = which == 0 ? wq : which == 1 ? wk : which == 2 ? wv : wo;
        int e0 = loc * 8;
        const float4* s = (const float4*)(src + e0);
        float4 a = s[0], c = s[1];
        bf16x8 o;
        o[0] = (bf16_t)a.x; o[1] = (bf16_t)a.y; o[2] = (bf16_t)a.z; o[3] = (bf16_t)a.w;
        o[4] = (bf16_t)c.x; o[5] = (bf16_t)c.y; o[6] = (bf16_t)c.z; o[7] = (bf16_t)c.w;
        *(bf16x8*)(wdst + (size_t)which * 1048576 + e0) = o;
    } else {
        // mask -> per-tile 64-bit masks (int32 vs byte-bool hedge)
        __shared__ int s_isbyte;
        if (tid == 0) s_isbyte = 0;
        __syncthreads();
        int any = 0;
        for (int i = tid; i < 4096; i += 256)
            if ((i & 3) && mraw[i]) any = 1;     // nonzero off-aligned byte => byte layout
        if (any) atomicOr(&s_isbyte, 1);
        __syncthreads();
        if (tid < 64) {
            int b = tid >> 5, kt = tid & 31;
            unsigned long long bits = 0;
            if (s_isbyte) {
                for (int j = 0; j < 64; ++j)
                    if (mraw[b * 2048 + kt * 64 + j]) bits |= 1ull << j;
            } else {
                const int* ri = (const int*)mraw;
                for (int j = 0; j < 64; ++j)
                    if (ri[b * 2048 + kt * 64 + j]) bits |= 1ull << j;
            }
            mbits[tid] = bits;
        }
    }
}

// ---------------- GEMM: C = A[M x 1024] * Bw[1024 x 1024]^T + bias ----------
// 2-barrier structure, 1-D XCD-chunked grid.
// mode 0 (QKV, 768 blocks): BOTH operands register-prefetched one K-step
//   ahead (loads issued after barrier #2, drained for free by the NEXT
//   iteration's barrier #1 vmcnt(0)); the barrier-to-barrier critical
//   section contains only cvt + 4 ds_write_b128 (lgkm, ~60 cyc). A = fp32
//   input ([T,B,F], z-selected), cvt'd in-register. z==0 (Q) pre-scaled by
//   0.125*log2(e); z==1/2 (K/V) masked rows zeroed in epilogue.
// mode 1 (out, 256 blocks): A bf16 (ctx) via gload16; out fp32 at [T,B,F].
__global__ __launch_bounds__(256) void gemm_kernel(const float* __restrict__ x0,
                                                   const float* __restrict__ x1,
                                                   const float* __restrict__ x2,
                                                   const bf16_t* __restrict__ Ab,
                                                   const bf16_t* __restrict__ Bw0,
                                                   const float* __restrict__ b0,
                                                   const float* __restrict__ b1,
                                                   const float* __restrict__ b2,
                                                   const unsigned long long* __restrict__ mbits,
                                                   bf16_t* __restrict__ outb,
                                                   float* __restrict__ outf,
                                                   int mode) {
    __shared__ __align__(16) bf16_t Asm[128 * 32];
    __shared__ __align__(16) bf16_t Bsm[128 * 32];
    const int tid = threadIdx.x;
    const int wave = tid >> 6, lane = tid & 63;
    const int g = lane >> 4, lr = lane & 15;

    // XCD-chunked block id (nb % 8 == 0 for both modes -> bijective)
    const int nb = (mode == 0) ? 768 : 256;
    const int chunk = nb >> 3;
    const int sid = (blockIdx.x & 7) * chunk + (blockIdx.x >> 3);
    const int z = sid >> 8;                  // 256 blocks per z-slice
    const int rem = sid & 255;
    const int m0 = (rem >> 3) * 128, n0 = (rem & 7) * 128;

    const float* Xf = z == 0 ? x0 : z == 1 ? x1 : x2;
    const bf16_t* Bw = Bw0 + (size_t)z * 1048576;
    const float* bias = z == 0 ? b0 : z == 1 ? b1 : b2;
    const float qsc = (mode == 0 && z == 0) ? 0.18033688f : 1.0f;  // 0.125*log2e
    const int wm = (wave >> 1) * 64, wn = (wave & 1) * 64;
    const int srow = wave * 32 + (lane >> 2);
    const int scol = (lane & 3) * 8;

    // fp32 A source (mode 0): row r=(b,t) of [T,B,F] -> f32 idx (t*2+b)*1024
    const int r0 = m0 + srow, r1 = r0 + 16;
    const size_t fb0 = (size_t)((r0 & 2047) * 2 + (r0 >> 11)) * 1024 + scol;
    const size_t fb1 = (size_t)((r1 & 2047) * 2 + (r1 >> 11)) * 1024 + scol;
    // B source rows (bf16)
    const bf16_t* gB0 = Bw + (size_t)(n0 + srow) * 1024 + scol;
    const bf16_t* gB1 = Bw + (size_t)(n0 + srow + 16) * 1024 + scol;
    // LDS dest bytes (identical to gload16's base + lane*16)
    char* dA0 = (char*)Asm + wave * 2048 + lane * 16;
    char* dA1 = dA0 + 1024;
    char* dB0 = (char*)Bsm + wave * 2048 + lane * 16;
    char* dB1 = dB0 + 1024;

    f32x4 acc[4][4] = {};
    float4 a00, a01, a10, a11;               // prefetched A registers (mode 0)
    bf16x8 br0, br1;                         // prefetched B registers (mode 0)

    if (mode == 0) {                         // prologue: regs for k0 = 0
        a00 = *(const float4*)(Xf + fb0);
        a01 = *(const float4*)(Xf + fb0 + 4);
        a10 = *(const float4*)(Xf + fb1);
        a11 = *(const float4*)(Xf + fb1 + 4);
        br0 = *(const bf16x8*)(gB0);
        br1 = *(const bf16x8*)(gB1);
    }

    for (int k0 = 0; k0 < 1024; k0 += 32) {
        __syncthreads();   // B1: prev iter's LDS reads done; drains the
                           //     register prefetch issued last iter (free)
        if (mode == 0) {
            bf16x8 w0, w1;
            w0[0] = (bf16_t)a00.x; w0[1] = (bf16_t)a00.y; w0[2] = (bf16_t)a00.z; w0[3] = (bf16_t)a00.w;
            w0[4] = (bf16_t)a01.x; w0[5] = (bf16_t)a01.y; w0[6] = (bf16_t)a01.z; w0[7] = (bf16_t)a01.w;
            w1[0] = (bf16_t)a10.x; w1[1] = (bf16_t)a10.y; w1[2] = (bf16_t)a10.z; w1[3] = (bf16_t)a10.w;
            w1[4] = (bf16_t)a11.x; w1[5] = (bf16_t)a11.y; w1[6] = (bf16_t)a11.z; w1[7] = (bf16_t)a11.w;
            *(bf16x8*)dA0 = w0;
            *(bf16x8*)dA1 = w1;
            *(bf16x8*)dB0 = br0;
            *(bf16x8*)dB1 = br1;
        } else {
            gload16(Ab + (size_t)r0 * 1024 + k0 + scol,               (char*)Asm + wave * 2048);
            gload16(Ab + (size_t)r1 * 1024 + k0 + scol,               (char*)Asm + wave * 2048 + 1024);
            gload16(gB0 + k0,                                         (char*)Bsm + wave * 2048);
            gload16(gB1 + k0,                                         (char*)Bsm + wave * 2048 + 1024);
        }
        __syncthreads();   // B2: mode 0 -> lgkm-only drain (no VMEM pending)

        // register prefetch for k0+32: issued before the MFMA block, drained
        // at the NEXT iteration's B1 -> full compute phase hides latency
        if (mode == 0 && k0 < 992) {
            a00 = *(const float4*)(Xf + fb0 + k0 + 32);
            a01 = *(const float4*)(Xf + fb0 + k0 + 36);
            a10 = *(const float4*)(Xf + fb1 + k0 + 32);
            a11 = *(const float4*)(Xf + fb1 + k0 + 36);
            br0 = *(const bf16x8*)(gB0 + k0 + 32);
            br1 = *(const bf16x8*)(gB1 + k0 + 32);
        }

        bf16x8 af[4], bfr[4];
        #pragma unroll
        for (int mi = 0; mi < 4; ++mi)
            af[mi] = *(const bf16x8*)(Asm + (wm + mi * 16 + lr) * 32 + g * 8);
        #pragma unroll
        for (int ni = 0; ni < 4; ++ni)
            bfr[ni] = *(const bf16x8*)(Bsm + (wn + ni * 16 + lr) * 32 + g * 8);
        #pragma unroll
        for (int mi = 0; mi < 4; ++mi)
            #pragma unroll
            for (int ni = 0; ni < 4; ++ni)
                acc[mi][ni] = __builtin_amdgcn_mfma_f32_16x16x32_bf16(af[mi], bfr[ni], acc[mi][ni], 0, 0, 0);
    }

    #pragma unroll
    for (int mi = 0; mi < 4; ++mi) {
        #pragma unroll
        for (int ni = 0; ni < 4; ++ni) {
            int n = n0 + wn + ni * 16 + lr;
            float bs = bias[n];
            #pragma unroll
            for (int i = 0; i < 4; ++i) {
                int m = m0 + wm + mi * 16 + 4 * g + i;
                float v = (acc[mi][ni][i] + bs) * qsc;
                int b = m >> 11, t = m & 2047;
                if (mode == 0) {
                    // zero masked key rows for K (z==1) and V (z==2)
                    if (z != 0) {
                        const bool mk = (mbits[b * 32 + (t >> 6)] >> (t & 63)) & 1;
                        if (mk) v = 0.f;
                    }
                    int hh = n >> 6, dk = n & 63;
                    outb[(size_t)z * 4194304 + ((size_t)(b * 16 + hh) * 2048 + t) * 64 + dk] = (bf16_t)v;
                } else {
                    outf[(size_t)t * 2048 + b * 1024 + n] = v;
                }
            }
        }
    }
}

// ---------------- flash attention (unchanged) -------------------------------
// 1-D grid 512, XCD-chunked. 4 waves; wave owns 32 q-rows (2 strips of 16).
// MASK-FREE inner loop: masked keys have K-row = 0 (score 0 -> p = 1) and
// V-row = 0 (no PV contribution); denominator = sacc - popcount(mask[b]).
__global__ __launch_bounds__(256, 2) void attn_kernel(const bf16_t* __restrict__ qh,
                                                      const bf16_t* __restrict__ kh,
                                                      const bf16_t* __restrict__ vh,
                                                      const unsigned long long* __restrict__ mbits,
                                                      bf16_t* __restrict__ ctx) {
    __shared__ __align__(16) bf16_t Ks[2][2][64 * 64];  // [pair-parity][tile] swizzled K
    __shared__ __align__(16) bf16_t Vs[2][2][64 * 64];  // [pair-parity][tile] subtiled V

    const int tid = threadIdx.x;
    const int wave = tid >> 6, lane = tid & 63;
    const int g = lane >> 4, lr = lane & 15;
    const int bid = blockIdx.x;
    const int sid = (bid & 7) * 64 + (bid >> 3);       // XCD-chunked (512 % 8 == 0)
    const int bh = sid >> 4, qc = sid & 15;
    const int b = bh >> 4, h = bh & 15;
    const int q0 = qc * 128;
    const bf16_t* Qg = qh + ((size_t)bh * 2048 + q0) * 64;
    const bf16_t* Kg = kh + (size_t)bh * 2048 * 64;
    const bf16_t* Vg = vh + (size_t)bh * 2048 * 64;
    const unsigned long long* mbp = mbits + b * 32;

    const int dstw = wave * 2048;            // wave's 2KB staging chunk (byte offset)
    const int dl = dstw + lane * 16;
    const int wq0 = wave * 32;
    const int vs0 = gofs(wave * 128 + lane);        // V source pre-permutation (bytes)
    const int vs1 = gofs(wave * 128 + 64 + lane);

    // stage Q tile (128 rows = 16 KB) through Ks[0]; Q pre-scaled by 0.125*log2e
    #pragma unroll
    for (int c = 0; c < 4; ++c)
        gload16((const char*)Qg + swz(wave * 4096 + c * 1024 + lane * 16),
                (char*)Ks[0] + wave * 4096 + c * 1024);
    __syncthreads();
    bf16x8 qf[2][2];
    #pragma unroll
    for (int s = 0; s < 2; ++s) {
        qf[s][0] = *(const bf16x8*)((const char*)Ks[0] + swz((wq0 + s * 16 + lr) * 128 + g * 16));
        qf[s][1] = *(const bf16x8*)((const char*)Ks[0] + swz((wq0 + s * 16 + lr) * 128 + 64 + g * 16));
    }
    __syncthreads();   // all waves done reading Q before staging overwrites Ks[0]

    // prologue: stage pair 0 (tiles 0,1)
    #pragma unroll
    for (int u = 0; u < 2; ++u) {
        const char* Kt = (const char*)(Kg + u * 4096);
        const char* Vt = (const char*)(Vg + u * 4096);
        gload16(Kt + swz(dl),        (char*)Ks[0][u] + dstw);
        gload16(Kt + swz(dl + 1024), (char*)Ks[0][u] + dstw + 1024);
        gload16(Vt + vs0,            (char*)Vs[0][u] + dstw);
        gload16(Vt + vs1,            (char*)Vs[0][u] + dstw + 1024);
    }

    // all-ones A fragment for row-sum MFMA
    bf16x8 ones;
    #pragma unroll
    for (int j = 0; j < 8; ++j) ones[j] = (bf16_t)1.0f;

    f32x4 cacc[2][4] = {};
    f32x4 sacc[2] = {};                      // row-sum accumulators (all regs equal)
    const unsigned vbase = (unsigned)(unsigned long long)(las_ptr)&Vs[0][0][0] + g * 512 + lr * 8;

    for (int m = 0; m < 16; ++m) {
        const int par = m & 1;
        __syncthreads();   // drains vmcnt: pair m staged; pair m-1 reads done

        // prefetch pair m+1 into the other parity (in flight across compute)
        if (m < 15) {
            #pragma unroll
            for (int u = 0; u < 2; ++u) {
                const char* Kn = (const char*)(Kg + (2 * m + 2 + u) * 4096);
                const char* Vn = (const char*)(Vg + (2 * m + 2 + u) * 4096);
                gload16(Kn + swz(dl),        (char*)Ks[par ^ 1][u] + dstw);
                gload16(Kn + swz(dl + 1024), (char*)Ks[par ^ 1][u] + dstw + 1024);
                gload16(Vn + vs0,            (char*)Vs[par ^ 1][u] + dstw);
                gload16(Vn + vs1,            (char*)Vs[par ^ 1][u] + dstw + 1024);
            }
        }

        // ---- QK^T for BOTH tiles (independent chains; s2[u] live together)
        f32x4 s2[2][2][4];                   // [tile][strip][st]
        __builtin_amdgcn_s_setprio(1);
        #pragma unroll
        for (int u = 0; u < 2; ++u) {
            const char* Kc = (const char*)Ks[par][u];
            #pragma unroll
            for (int st = 0; st < 4; ++st) {
                bf16x8 kf0 = *(const bf16x8*)(Kc + swz((st * 16 + lr) * 128 + g * 16));
                bf16x8 kf1 = *(const bf16x8*)(Kc + swz((st * 16 + lr) * 128 + 64 + g * 16));
                #pragma unroll
                for (int s = 0; s < 2; ++s) {
                    f32x4 zz = {};
                    zz = __builtin_amdgcn_mfma_f32_16x16x32_bf16(kf0, qf[s][0], zz, 0, 0, 0);
                    zz = __builtin_amdgcn_mfma_f32_16x16x32_bf16(kf1, qf[s][1], zz, 0, 0, 0);
                    s2[u][s][st] = zz;
                }
            }
        }
        __builtin_amdgcn_s_setprio(0);

        // ---- softmax (mask-free: p = exp2(s)) + pack + PV per tile;
        // tile-1's softmax overlaps tile-0's PV MFMAs
        #pragma unroll
        for (int u = 0; u < 2; ++u) {
            #pragma unroll
            for (int st = 0; st < 4; ++st) {
                #pragma unroll
                for (int i = 0; i < 4; ++i) {
                    s2[u][0][st][i] = EXP2F(s2[u][0][st][i]);
                    s2[u][1][st][i] = EXP2F(s2[u][1][st][i]);
                }
            }
            // pack P^T B-fragments: slot j -> key 32kk + 16(j>>2) + 4g + (j&3)
            bf16x8 pb[2][2];
            #pragma unroll
            for (int s = 0; s < 2; ++s)
                #pragma unroll
                for (int kk = 0; kk < 2; ++kk)
                    #pragma unroll
                    for (int j = 0; j < 8; ++j)
                        pb[s][kk][j] = (bf16_t)s2[u][s][2 * kk + (j >> 2)][j & 3];

            // PV: A = V^T fragments via hardware transpose read (16 x b64_tr_b16)
            const unsigned vb = vbase + (unsigned)par * 16384u + (unsigned)u * 8192u;
            u32x2 t[2][2][4];
            TRREAD(t[0][0][0], vb, 0);    TRREAD(t[0][0][1], vb, 128);
            TRREAD(t[0][0][2], vb, 256);  TRREAD(t[0][0][3], vb, 384);
            TRREAD(t[0][1][0], vb, 2048); TRREAD(t[0][1][1], vb, 2176);
            TRREAD(t[0][1][2], vb, 2304); TRREAD(t[0][1][3], vb, 2432);
            TRREAD(t[1][0][0], vb, 4096); TRREAD(t[1][0][1], vb, 4224);
            TRREAD(t[1][0][2], vb, 4352); TRREAD(t[1][0][3], vb, 4480);
            TRREAD(t[1][1][0], vb, 6144); TRREAD(t[1][1][1], vb, 6272);
            TRREAD(t[1][1][2], vb, 6400); TRREAD(t[1][1][3], vb, 6528);
            asm volatile("s_waitcnt lgkmcnt(0)" ::: "memory");
            __builtin_amdgcn_sched_barrier(0);   // rule 18: keep MFMAs after the wait
            __builtin_amdgcn_s_setprio(1);
            #pragma unroll
            for (int kk = 0; kk < 2; ++kk) {
                // row-sum MFMA: D[row][q] = sum_k P^T[k][q] (one per strip per kk)
                sacc[0] = __builtin_amdgcn_mfma_f32_16x16x32_bf16(ones, pb[0][kk], sacc[0], 0, 0, 0);
                sacc[1] = __builtin_amdgcn_mfma_f32_16x16x32_bf16(ones, pb[1][kk], sacc[1], 0, 0, 0);
                #pragma unroll
                for (int ni = 0; ni < 4; ++ni) {
                    union { u32x2 q[2]; bf16x8 v8; } uu;
                    uu.q[0] = t[kk][0][ni];
                    uu.q[1] = t[kk][1][ni];
                    #pragma unroll
                    for (int s = 0; s < 2; ++s)
                        cacc[s][ni] = __builtin_amdgcn_mfma_f32_16x16x32_bf16(uu.v8, pb[s][kk], cacc[s][ni], 0, 0, 0);
                }
            }
            __builtin_amdgcn_s_setprio(0);
        }
    }

    // epilogue: denominator = sacc - nmasked (masked keys contribute exactly
    // 1.0 each: K-row zeroed -> s=0 -> p=1; V-row zeroed -> no PV effect)
    float nm = 0.f;
    #pragma unroll
    for (int i = 0; i < 32; ++i)
        nm += (float)__popcll(mbp[i]);
    #pragma unroll
    for (int s = 0; s < 2; ++s) {
        const float rl = RCPF(sacc[s][0] - nm);
        const int trow = q0 + wq0 + s * 16 + lr;
        #pragma unroll
        for (int ni = 0; ni < 4; ++ni) {
            bf16x4 o;
            #pragma unroll
            for (int i = 0; i < 4; ++i)
                o[i] = (bf16_t)(cacc[s][ni][i] * rl);
            *(bf16x4*)(ctx + ((size_t)b * 2048 + trow) * 1024 + h * 64 + ni * 16 + 4 * g) = o;
        }
    }
}

// ---------------- launch ----------------------------------------------------
extern "C" void kernel_launch(void* const* d_in, const int* in_sizes, int n_in,
                              void* d_out, int out_size, void* d_ws, size_t ws_size,
                              hipStream_t stream) {
    const float* query = (const float*)d_in[0];
    const float* key_  = (const float*)d_in[1];
    const float* value = (const float*)d_in[2];
    const unsigned char* kpm_raw = (const unsigned char*)d_in[3];
    const float* Wq = (const float*)d_in[4];
    const float* bq = (const float*)d_in[5];
    const float* Wk = (const float*)d_in[6];
    const float* bk = (const float*)d_in[7];
    const float* Wv = (const float*)d_in[8];
    const float* bv = (const float*)d_in[9];
    const float* Wo = (const float*)d_in[10];
    const float* bo = (const float*)d_in[11];
    float* out = (float*)d_out;

    char* ws = (char*)d_ws;
    size_t off = 0;
    auto alloc = [&](size_t bytes) {
        char* p = ws + off;
        off += (bytes + 255) & ~(size_t)255;
        return p;
    };
    const size_t SZ_X = (size_t)4096 * 1024 * sizeof(bf16_t);  // 8 MB
    const size_t SZ_W = (size_t)1024 * 1024 * sizeof(bf16_t);  // 2 MB
    bf16_t* wqb = (bf16_t*)alloc(SZ_W);   // wqb..wob contiguous (z-indexed)
    bf16_t* wkb = (bf16_t*)alloc(SZ_W);
    bf16_t* wvb = (bf16_t*)alloc(SZ_W);
    bf16_t* wob = (bf16_t*)alloc(SZ_W);
    bf16_t* qhB = (bf16_t*)alloc(SZ_X);   // qhB,khB,vhB contiguous (z-indexed)
    bf16_t* khB = (bf16_t*)alloc(SZ_X);
    bf16_t* vhB = (bf16_t*)alloc(SZ_X);
    bf16_t* ctxB = (bf16_t*)alloc(SZ_X);
    unsigned long long* mbits = (unsigned long long*)alloc(64 * sizeof(unsigned long long));
    (void)wkb; (void)wvb;

    // prep: 2048 (w4 cvt) + 1 (mask) blocks
    prep_all_kernel<<<2049, 256, 0, stream>>>(Wq, Wk, Wv, Wo, kpm_raw, wqb, mbits);

    // QKV projections: fp32 A direct from inputs; 768 blocks XCD-chunked
    gemm_kernel<<<768, 256, 0, stream>>>(query, key_, value, nullptr, wqb,
                                         bq, bk, bv, mbits, qhB, nullptr, 0);

    attn_kernel<<<512, 256, 0, stream>>>(qhB, khB, vhB, mbits, ctxB);

    // out projection: bf16 A (ctx); 256 blocks
    gemm_kernel<<<256, 256, 0, stream>>>(nullptr, nullptr, nullptr, ctxB, wob,
                                         bo, bo, bo, mbits, nullptr, out, 1);
}

// Round 15
// 137.373 us; speedup vs baseline: 1.0796x; 1.0796x over previous
//
#include <hip/hip_runtime.h>
#include <hip/hip_bf16.h>
#include <stdint.h>

// ESPNET MultiHeadedAttention: T=2048 B=2 F=1024 H=16 DK=64
// prep(w-cvt+mask) -> QKV proj GEMM (128x64 tile, 1536 blocks = 6/CU for
// latency hiding via TLP; r13 inner structure: A fp32 reg-prefetch + cvt +
// ds_write, B gload16, 2 barriers; Q pre-scaled, masked K/V rows zeroed) ->
// flash attn (mask-free, unroll-2 pairs, swapped QK^T, static-max softmax,
// ones-MFMA row-sums, tr_b16 V, XCD grid) -> out GEMM (128x128, gload16)

typedef __bf16 bf16_t;
typedef __bf16 bf16x4 __attribute__((ext_vector_type(4)));
typedef __bf16 bf16x8 __attribute__((ext_vector_type(8)));
typedef float f32x4 __attribute__((ext_vector_type(4)));
typedef unsigned int u32x2 __attribute__((ext_vector_type(2)));

typedef const __attribute__((address_space(1))) void* gas_ptr;
typedef __attribute__((address_space(3))) void* las_ptr;

__device__ __forceinline__ void gload16(const void* g, void* lds) {
    // async global->LDS, 16B/lane; LDS dest = wave-uniform base + lane*16
    __builtin_amdgcn_global_load_lds((gas_ptr)g, (las_ptr)lds, 16, 0, 0);
}

// XOR swizzle for 128-B-row tiles: involution, moves 16B blocks, stays in-row
__device__ __forceinline__ int swz(int o) { return o ^ (((o >> 7) & 7) << 4); }

// V staging pre-permutation: 16B chunk c of subtiled LDS [key/4][d/16][4][16]
// comes from global byte offset (key*128 + d*2) of the 64x64 V tile.
__device__ __forceinline__ int gofs(int c) {
    return ((c >> 5) << 9) + (((c >> 1) & 3) << 7) + (((c >> 3) & 3) << 5) + ((c & 1) << 4);
}

#define TRREAD(dst, addr, IMM) \
    asm volatile("ds_read_b64_tr_b16 %0, %1 offset:" #IMM : "=v"(dst) : "v"(addr))

#if __has_builtin(__builtin_amdgcn_exp2f)
#define EXP2F(x) __builtin_amdgcn_exp2f(x)
#else
#define EXP2F(x) exp2f(x)
#endif
#if __has_builtin(__builtin_amdgcn_rcpf)
#define RCPF(x) __builtin_amdgcn_rcpf(x)
#else
#define RCPF(x) (1.0f / (x))
#endif

// ---------------- prep: cvt w4 + mask bits ----------------------------------
__global__ __launch_bounds__(256) void prep_all_kernel(const float* __restrict__ wq,
                                                       const float* __restrict__ wk,
                                                       const float* __restrict__ wv,
                                                       const float* __restrict__ wo,
                                                       const unsigned char* __restrict__ mraw,
                                                       bf16_t* __restrict__ wdst,
                                                       unsigned long long* __restrict__ mbits) {
    const int bidx = blockIdx.x;
    const int tid = threadIdx.x;
    if (bidx < 2048) {
        // fp32 -> bf16, 4 weight matrices (contiguous dst)
        int idx = bidx * 256 + tid;
        int which = idx >> 17;               // 131072 threads per matrix
        int loc = idx & 131071;
        const float* src = which == 0 ? wq : which == 1 ? wk : which == 2 ? wv : wo;
        int e0 = loc * 8;
        const float4* s = (const float4*)(src + e0);
        float4 a = s[0], c = s[1];
        bf16x8 o;
        o[0] = (bf16_t)a.x; o[1] = (bf16_t)a.y; o[2] = (bf16_t)a.z; o[3] = (bf16_t)a.w;
        o[4] = (bf16_t)c.x; o[5] = (bf16_t)c.y; o[6] = (bf16_t)c.z; o[7] = (bf16_t)c.w;
        *(bf16x8*)(wdst + (size_t)which * 1048576 + e0) = o;
    } else {
        // mask -> per-tile 64-bit masks (int32 vs byte-bool hedge)
        __shared__ int s_isbyte;
        if (tid == 0) s_isbyte = 0;
        __syncthreads();
        int any = 0;
        for (int i = tid; i < 4096; i += 256)
            if ((i & 3) && mraw[i]) any = 1;     // nonzero off-aligned byte => byte layout
        if (any) atomicOr(&s_isbyte, 1);
        __syncthreads();
        if (tid < 64) {
            int b = tid >> 5, kt = tid & 31;
            unsigned long long bits = 0;
            if (s_isbyte) {
                for (int j = 0; j < 64; ++j)
                    if (mraw[b * 2048 + kt * 64 + j]) bits |= 1ull << j;
            } else {
                const int* ri = (const int*)mraw;
                for (int j = 0; j < 64; ++j)
                    if (ri[b * 2048 + kt * 64 + j]) bits |= 1ull << j;
            }
            mbits[tid] = bits;
        }
    }
}

// ---------------- QKV GEMM: 128x64 tile, 1536 blocks (6/CU) -----------------
// r13 inner structure: A = fp32 input, register-prefetched one K-step ahead,
// cvt + ds_write between barriers; B staged via one gload16 per wave.
// z = sid/512 selects projection; z==0 (Q) pre-scaled by 0.125*log2(e);
// z==1/2 (K/V) masked key rows zeroed in epilogue. Out bf16 [B,H,T,DK] (+z*4M).
__global__ __launch_bounds__(256) void gemm_qkv_kernel(const float* __restrict__ x0,
                                                       const float* __restrict__ x1,
                                                       const float* __restrict__ x2,
                                                       const bf16_t* __restrict__ Bw0,
                                                       const float* __restrict__ b0,
                                                       const float* __restrict__ b1,
                                                       const float* __restrict__ b2,
                                                       const unsigned long long* __restrict__ mbits,
                                                       bf16_t* __restrict__ outb) {
    __shared__ __align__(16) bf16_t Asm[128 * 32];   // 8 KB
    __shared__ __align__(16) bf16_t Bsm[64 * 32];    // 4 KB
    const int tid = threadIdx.x;
    const int wave = tid >> 6, lane = tid & 63;
    const int g = lane >> 4, lr = lane & 15;

    // XCD-chunked block id: 1536 % 8 == 0, chunk = 192 (bijective)
    const int sid = (blockIdx.x & 7) * 192 + (blockIdx.x >> 3);
    const int z = sid >> 9;                  // 512 blocks per z-slice
    const int rem = sid & 511;
    const int m0 = (rem >> 4) * 128, n0 = (rem & 15) * 64;  // consecutive sids share m0

    const float* Xf = z == 0 ? x0 : z == 1 ? x1 : x2;
    const bf16_t* Bw = Bw0 + (size_t)z * 1048576;
    const float* bias = z == 0 ? b0 : z == 1 ? b1 : b2;
    const float qsc = (z == 0) ? 0.18033688f : 1.0f;   // 0.125*log2e
    const int wm = (wave >> 1) * 64, wn = (wave & 1) * 32;
    const int srow = wave * 32 + (lane >> 2);
    const int scol = (lane & 3) * 8;

    // fp32 A source: row r=(b,t) of [T,B,F] -> f32 idx (t*2+b)*1024
    const int r0 = m0 + srow, r1 = r0 + 16;
    const size_t fb0 = (size_t)((r0 & 2047) * 2 + (r0 >> 11)) * 1024 + scol;
    const size_t fb1 = (size_t)((r1 & 2047) * 2 + (r1 >> 11)) * 1024 + scol;
    // B source: 16 rows per wave
    const bf16_t* gB = Bw + (size_t)(n0 + wave * 16 + (lane >> 2)) * 1024 + scol;
    // LDS dest bytes
    char* dA0 = (char*)Asm + wave * 2048 + lane * 16;
    char* dA1 = dA0 + 1024;
    char* dB  = (char*)Bsm + wave * 1024;

    f32x4 acc[4][2] = {};
    float4 a00, a01, a10, a11;               // prefetched A registers

    a00 = *(const float4*)(Xf + fb0);        // prologue: A regs for k0 = 0
    a01 = *(const float4*)(Xf + fb0 + 4);
    a10 = *(const float4*)(Xf + fb1);
    a11 = *(const float4*)(Xf + fb1 + 4);

    for (int k0 = 0; k0 < 1024; k0 += 32) {
        __syncthreads();   // B1: prev LDS reads done; drains A-reg prefetch
        {
            bf16x8 w0, w1;
            w0[0] = (bf16_t)a00.x; w0[1] = (bf16_t)a00.y; w0[2] = (bf16_t)a00.z; w0[3] = (bf16_t)a00.w;
            w0[4] = (bf16_t)a01.x; w0[5] = (bf16_t)a01.y; w0[6] = (bf16_t)a01.z; w0[7] = (bf16_t)a01.w;
            w1[0] = (bf16_t)a10.x; w1[1] = (bf16_t)a10.y; w1[2] = (bf16_t)a10.z; w1[3] = (bf16_t)a10.w;
            w1[4] = (bf16_t)a11.x; w1[5] = (bf16_t)a11.y; w1[6] = (bf16_t)a11.z; w1[7] = (bf16_t)a11.w;
            *(bf16x8*)dA0 = w0;
            *(bf16x8*)dA1 = w1;
            gload16(gB + k0, dB);
        }
        __syncthreads();   // B2: Asm (lgkm) + Bsm (vm) staged

        // software-pipelined A prefetch for k0+32 (drained at next B1)
        if (k0 < 992) {
            a00 = *(const float4*)(Xf + fb0 + k0 + 32);
            a01 = *(const float4*)(Xf + fb0 + k0 + 36);
            a10 = *(const float4*)(Xf + fb1 + k0 + 32);
            a11 = *(const float4*)(Xf + fb1 + k0 + 36);
        }

        bf16x8 af[4], bfr[2];
        #pragma unroll
        for (int mi = 0; mi < 4; ++mi)
            af[mi] = *(const bf16x8*)(Asm + (wm + mi * 16 + lr) * 32 + g * 8);
        #pragma unroll
        for (int ni = 0; ni < 2; ++ni)
            bfr[ni] = *(const bf16x8*)(Bsm + (wn + ni * 16 + lr) * 32 + g * 8);
        #pragma unroll
        for (int mi = 0; mi < 4; ++mi)
            #pragma unroll
            for (int ni = 0; ni < 2; ++ni)
                acc[mi][ni] = __builtin_amdgcn_mfma_f32_16x16x32_bf16(af[mi], bfr[ni], acc[mi][ni], 0, 0, 0);
    }

    #pragma unroll
    for (int mi = 0; mi < 4; ++mi) {
        #pragma unroll
        for (int ni = 0; ni < 2; ++ni) {
            int n = n0 + wn + ni * 16 + lr;
            float bs = bias[n];
            #pragma unroll
            for (int i = 0; i < 4; ++i) {
                int m = m0 + wm + mi * 16 + 4 * g + i;
                float v = (acc[mi][ni][i] + bs) * qsc;
                int b = m >> 11, t = m & 2047;
                if (z != 0) {                // zero masked key rows for K/V
                    const bool mk = (mbits[b * 32 + (t >> 6)] >> (t & 63)) & 1;
                    if (mk) v = 0.f;
                }
                int hh = n >> 6, dk = n & 63;
                outb[(size_t)z * 4194304 + ((size_t)(b * 16 + hh) * 2048 + t) * 64 + dk] = (bf16_t)v;
            }
        }
    }
}

// ---------------- out GEMM: 128x128, 256 blocks (r13 mode-1) ----------------
__global__ __launch_bounds__(256) void gemm_out_kernel(const bf16_t* __restrict__ Ab,
                                                       const bf16_t* __restrict__ Bw,
                                                       const float* __restrict__ bias,
                                                       float* __restrict__ outf) {
    __shared__ __align__(16) bf16_t Asm[128 * 32];
    __shared__ __align__(16) bf16_t Bsm[128 * 32];
    const int tid = threadIdx.x;
    const int wave = tid >> 6, lane = tid & 63;
    const int g = lane >> 4, lr = lane & 15;

    const int sid = (blockIdx.x & 7) * 32 + (blockIdx.x >> 3);   // 256 % 8 == 0
    const int m0 = (sid >> 3) * 128, n0 = (sid & 7) * 128;
    const int wm = (wave >> 1) * 64, wn = (wave & 1) * 64;
    const int srow = wave * 32 + (lane >> 2);
    const int scol = (lane & 3) * 8;
    const int r0 = m0 + srow, r1 = r0 + 16;

    f32x4 acc[4][4] = {};

    for (int k0 = 0; k0 < 1024; k0 += 32) {
        __syncthreads();
        gload16(Ab + (size_t)r0 * 1024 + k0 + scol,               (char*)Asm + wave * 2048);
        gload16(Ab + (size_t)r1 * 1024 + k0 + scol,               (char*)Asm + wave * 2048 + 1024);
        gload16(Bw + (size_t)(n0 + srow) * 1024 + k0 + scol,      (char*)Bsm + wave * 2048);
        gload16(Bw + (size_t)(n0 + srow + 16) * 1024 + k0 + scol, (char*)Bsm + wave * 2048 + 1024);
        __syncthreads();

        bf16x8 af[4], bfr[4];
        #pragma unroll
        for (int mi = 0; mi < 4; ++mi)
            af[mi] = *(const bf16x8*)(Asm + (wm + mi * 16 + lr) * 32 + g * 8);
        #pragma unroll
        for (int ni = 0; ni < 4; ++ni)
            bfr[ni] = *(const bf16x8*)(Bsm + (wn + ni * 16 + lr) * 32 + g * 8);
        #pragma unroll
        for (int mi = 0; mi < 4; ++mi)
            #pragma unroll
            for (int ni = 0; ni < 4; ++ni)
                acc[mi][ni] = __builtin_amdgcn_mfma_f32_16x16x32_bf16(af[mi], bfr[ni], acc[mi][ni], 0, 0, 0);
    }

    #pragma unroll
    for (int mi = 0; mi < 4; ++mi) {
        #pragma unroll
        for (int ni = 0; ni < 4; ++ni) {
            int n = n0 + wn + ni * 16 + lr;
            float bs = bias[n];
            #pragma unroll
            for (int i = 0; i < 4; ++i) {
                int m = m0 + wm + mi * 16 + 4 * g + i;
                int b = m >> 11, t = m & 2047;
                outf[(size_t)t * 2048 + b * 1024 + n] = acc[mi][ni][i] + bs;
            }
        }
    }
}

// ---------------- flash attention (unchanged) -------------------------------
// 1-D grid 512, XCD-chunked. 4 waves; wave owns 32 q-rows (2 strips of 16).
// MASK-FREE inner loop: masked keys have K-row = 0 (score 0 -> p = 1) and
// V-row = 0 (no PV contribution); denominator = sacc - popcount(mask[b]).
__global__ __launch_bounds__(256, 2) void attn_kernel(const bf16_t* __restrict__ qh,
                                                      const bf16_t* __restrict__ kh,
                                                      const bf16_t* __restrict__ vh,
                                                      const unsigned long long* __restrict__ mbits,
                                                      bf16_t* __restrict__ ctx) {
    __shared__ __align__(16) bf16_t Ks[2][2][64 * 64];  // [pair-parity][tile] swizzled K
    __shared__ __align__(16) bf16_t Vs[2][2][64 * 64];  // [pair-parity][tile] subtiled V

    const int tid = threadIdx.x;
    const int wave = tid >> 6, lane = tid & 63;
    const int g = lane >> 4, lr = lane & 15;
    const int bid = blockIdx.x;
    const int sid = (bid & 7) * 64 + (bid >> 3);       // XCD-chunked (512 % 8 == 0)
    const int bh = sid >> 4, qc = sid & 15;
    const int b = bh >> 4, h = bh & 15;
    const int q0 = qc * 128;
    const bf16_t* Qg = qh + ((size_t)bh * 2048 + q0) * 64;
    const bf16_t* Kg = kh + (size_t)bh * 2048 * 64;
    const bf16_t* Vg = vh + (size_t)bh * 2048 * 64;
    const unsigned long long* mbp = mbits + b * 32;

    const int dstw = wave * 2048;            // wave's 2KB staging chunk (byte offset)
    const int dl = dstw + lane * 16;
    const int wq0 = wave * 32;
    const int vs0 = gofs(wave * 128 + lane);        // V source pre-permutation (bytes)
    const int vs1 = gofs(wave * 128 + 64 + lane);

    // stage Q tile (128 rows = 16 KB) through Ks[0]; Q pre-scaled by 0.125*log2e
    #pragma unroll
    for (int c = 0; c < 4; ++c)
        gload16((const char*)Qg + swz(wave * 4096 + c * 1024 + lane * 16),
                (char*)Ks[0] + wave * 4096 + c * 1024);
    __syncthreads();
    bf16x8 qf[2][2];
    #pragma unroll
    for (int s = 0; s < 2; ++s) {
        qf[s][0] = *(const bf16x8*)((const char*)Ks[0] + swz((wq0 + s * 16 + lr) * 128 + g * 16));
        qf[s][1] = *(const bf16x8*)((const char*)Ks[0] + swz((wq0 + s * 16 + lr) * 128 + 64 + g * 16));
    }
    __syncthreads();   // all waves done reading Q before staging overwrites Ks[0]

    // prologue: stage pair 0 (tiles 0,1)
    #pragma unroll
    for (int u = 0; u < 2; ++u) {
        const char* Kt = (const char*)(Kg + u * 4096);
        const char* Vt = (const char*)(Vg + u * 4096);
        gload16(Kt + swz(dl),        (char*)Ks[0][u] + dstw);
        gload16(Kt + swz(dl + 1024), (char*)Ks[0][u] + dstw + 1024);
        gload16(Vt + vs0,            (char*)Vs[0][u] + dstw);
        gload16(Vt + vs1,            (char*)Vs[0][u] + dstw + 1024);
    }

    // all-ones A fragment for row-sum MFMA
    bf16x8 ones;
    #pragma unroll
    for (int j = 0; j < 8; ++j) ones[j] = (bf16_t)1.0f;

    f32x4 cacc[2][4] = {};
    f32x4 sacc[2] = {};                      // row-sum accumulators (all regs equal)
    const unsigned vbase = (unsigned)(unsigned long long)(las_ptr)&Vs[0][0][0] + g * 512 + lr * 8;

    for (int m = 0; m < 16; ++m) {
        const int par = m & 1;
        __syncthreads();   // drains vmcnt: pair m staged; pair m-1 reads done

        // prefetch pair m+1 into the other parity (in flight across compute)
        if (m < 15) {
            #pragma unroll
            for (int u = 0; u < 2; ++u) {
                const char* Kn = (const char*)(Kg + (2 * m + 2 + u) * 4096);
                const char* Vn = (const char*)(Vg + (2 * m + 2 + u) * 4096);
                gload16(Kn + swz(dl),        (char*)Ks[par ^ 1][u] + dstw);
                gload16(Kn + swz(dl + 1024), (char*)Ks[par ^ 1][u] + dstw + 1024);
                gload16(Vn + vs0,            (char*)Vs[par ^ 1][u] + dstw);
                gload16(Vn + vs1,            (char*)Vs[par ^ 1][u] + dstw + 1024);
            }
        }

        // ---- QK^T for BOTH tiles (independent chains; s2[u] live together)
        f32x4 s2[2][2][4];                   // [tile][strip][st]
        __builtin_amdgcn_s_setprio(1);
        #pragma unroll
        for (int u = 0; u < 2; ++u) {
            const char* Kc = (const char*)Ks[par][u];
            #pragma unroll
            for (int st = 0; st < 4; ++st) {
                bf16x8 kf0 = *(const bf16x8*)(Kc + swz((st * 16 + lr) * 128 + g * 16));
                bf16x8 kf1 = *(const bf16x8*)(Kc + swz((st * 16 + lr) * 128 + 64 + g * 16));
                #pragma unroll
                for (int s = 0; s < 2; ++s) {
                    f32x4 zz = {};
                    zz = __builtin_amdgcn_mfma_f32_16x16x32_bf16(kf0, qf[s][0], zz, 0, 0, 0);
                    zz = __builtin_amdgcn_mfma_f32_16x16x32_bf16(kf1, qf[s][1], zz, 0, 0, 0);
                    s2[u][s][st] = zz;
                }
            }
        }
        __builtin_amdgcn_s_setprio(0);

        // ---- softmax (mask-free: p = exp2(s)) + pack + PV per tile;
        // tile-1's softmax overlaps tile-0's PV MFMAs
        #pragma unroll
        for (int u = 0; u < 2; ++u) {
            #pragma unroll
            for (int st = 0; st < 4; ++st) {
                #pragma unroll
                for (int i = 0; i < 4; ++i) {
                    s2[u][0][st][i] = EXP2F(s2[u][0][st][i]);
                    s2[u][1][st][i] = EXP2F(s2[u][1][st][i]);
                }
            }
            // pack P^T B-fragments: slot j -> key 32kk + 16(j>>2) + 4g + (j&3)
            bf16x8 pb[2][2];
            #pragma unroll
            for (int s = 0; s < 2; ++s)
                #pragma unroll
                for (int kk = 0; kk < 2; ++kk)
                    #pragma unroll
                    for (int j = 0; j < 8; ++j)
                        pb[s][kk][j] = (bf16_t)s2[u][s][2 * kk + (j >> 2)][j & 3];

            // PV: A = V^T fragments via hardware transpose read (16 x b64_tr_b16)
            const unsigned vb = vbase + (unsigned)par * 16384u + (unsigned)u * 8192u;
            u32x2 t[2][2][4];
            TRREAD(t[0][0][0], vb, 0);    TRREAD(t[0][0][1], vb, 128);
            TRREAD(t[0][0][2], vb, 256);  TRREAD(t[0][0][3], vb, 384);
            TRREAD(t[0][1][0], vb, 2048); TRREAD(t[0][1][1], vb, 2176);
            TRREAD(t[0][1][2], vb, 2304); TRREAD(t[0][1][3], vb, 2432);
            TRREAD(t[1][0][0], vb, 4096); TRREAD(t[1][0][1], vb, 4224);
            TRREAD(t[1][0][2], vb, 4352); TRREAD(t[1][0][3], vb, 4480);
            TRREAD(t[1][1][0], vb, 6144); TRREAD(t[1][1][1], vb, 6272);
            TRREAD(t[1][1][2], vb, 6400); TRREAD(t[1][1][3], vb, 6528);
            asm volatile("s_waitcnt lgkmcnt(0)" ::: "memory");
            __builtin_amdgcn_sched_barrier(0);   // rule 18: keep MFMAs after the wait
            __builtin_amdgcn_s_setprio(1);
            #pragma unroll
            for (int kk = 0; kk < 2; ++kk) {
                // row-sum MFMA: D[row][q] = sum_k P^T[k][q] (one per strip per kk)
                sacc[0] = __builtin_amdgcn_mfma_f32_16x16x32_bf16(ones, pb[0][kk], sacc[0], 0, 0, 0);
                sacc[1] = __builtin_amdgcn_mfma_f32_16x16x32_bf16(ones, pb[1][kk], sacc[1], 0, 0, 0);
                #pragma unroll
                for (int ni = 0; ni < 4; ++ni) {
                    union { u32x2 q[2]; bf16x8 v8; } uu;
                    uu.q[0] = t[kk][0][ni];
                    uu.q[1] = t[kk][1][ni];
                    #pragma unroll
                    for (int s = 0; s < 2; ++s)
                        cacc[s][ni] = __builtin_amdgcn_mfma_f32_16x16x32_bf16(uu.v8, pb[s][kk], cacc[s][ni], 0, 0, 0);
                }
            }
            __builtin_amdgcn_s_setprio(0);
        }
    }

    // epilogue: denominator = sacc - nmasked (masked keys contribute exactly
    // 1.0 each: K-row zeroed -> s=0 -> p=1; V-row zeroed -> no PV effect)
    float nm = 0.f;
    #pragma unroll
    for (int i = 0; i < 32; ++i)
        nm += (float)__popcll(mbp[i]);
    #pragma unroll
    for (int s = 0; s < 2; ++s) {
        const float rl = RCPF(sacc[s][0] - nm);
        const int trow = q0 + wq0 + s * 16 + lr;
        #pragma unroll
        for (int ni = 0; ni < 4; ++ni) {
            bf16x4 o;
            #pragma unroll
            for (int i = 0; i < 4; ++i)
                o[i] = (bf16_t)(cacc[s][ni][i] * rl);
            *(bf16x4*)(ctx + ((size_t)b * 2048 + trow) * 1024 + h * 64 + ni * 16 + 4 * g) = o;
        }
    }
}

// ---------------- launch ----------------------------------------------------
extern "C" void kernel_launch(void* const* d_in, const int* in_sizes, int n_in,
                              void* d_out, int out_size, void* d_ws, size_t ws_size,
                              hipStream_t stream) {
    const float* query = (const float*)d_in[0];
    const float* key_  = (const float*)d_in[1];
    const float* value = (const float*)d_in[2];
    const unsigned char* kpm_raw = (const unsigned char*)d_in[3];
    const float* Wq = (const float*)d_in[4];
    const float* bq = (const float*)d_in[5];
    const float* Wk = (const float*)d_in[6];
    const float* bk = (const float*)d_in[7];
    const float* Wv = (const float*)d_in[8];
    const float* bv = (const float*)d_in[9];
    const float* Wo = (const float*)d_in[10];
    const float* bo = (const float*)d_in[11];
    float* out = (float*)d_out;

    char* ws = (char*)d_ws;
    size_t off = 0;
    auto alloc = [&](size_t bytes) {
        char* p = ws + off;
        off += (bytes + 255) & ~(size_t)255;
        return p;
    };
    const size_t SZ_X = (size_t)4096 * 1024 * sizeof(bf16_t);  // 8 MB
    const size_t SZ_W = (size_t)1024 * 1024 * sizeof(bf16_t);  // 2 MB
    bf16_t* wqb = (bf16_t*)alloc(SZ_W);   // wqb..wob contiguous (z-indexed)
    bf16_t* wkb = (bf16_t*)alloc(SZ_W);
    bf16_t* wvb = (bf16_t*)alloc(SZ_W);
    bf16_t* wob = (bf16_t*)alloc(SZ_W);
    bf16_t* qhB = (bf16_t*)alloc(SZ_X);   // qhB,khB,vhB contiguous (z-indexed)
    bf16_t* khB = (bf16_t*)alloc(SZ_X);
    bf16_t* vhB = (bf16_t*)alloc(SZ_X);
    bf16_t* ctxB = (bf16_t*)alloc(SZ_X);
    unsigned long long* mbits = (unsigned long long*)alloc(64 * sizeof(unsigned long long));
    (void)wkb; (void)wvb;

    // prep: 2048 (w4 cvt) + 1 (mask) blocks
    prep_all_kernel<<<2049, 256, 0, stream>>>(Wq, Wk, Wv, Wo, kpm_raw, wqb, mbits);

    // QKV projections: 128x64 tiles, 1536 blocks (6/CU), XCD-chunked
    gemm_qkv_kernel<<<1536, 256, 0, stream>>>(query, key_, value, wqb,
                                              bq, bk, bv, mbits, qhB);

    attn_kernel<<<512, 256, 0, stream>>>(qhB, khB, vhB, mbits, ctxB);

    // out projection: 128x128, 256 blocks
    gemm_out_kernel<<<256, 256, 0, stream>>>(ctxB, wob, bo, out);
}

// Round 16
// 127.851 us; speedup vs baseline: 1.1600x; 1.0745x over previous
//
#include <hip/hip_runtime.h>
#include <hip/hip_bf16.h>
#include <stdint.h>

// ESPNET MultiHeadedAttention: T=2048 B=2 F=1024 H=16 DK=64
// prep(w-cvt+mask) -> QKV proj GEMM (128x128, 2-barrier all-gload16: A staged
// as fp32 via swizzled-source gload16, cvt on LDS->fragment read; B bf16
// gload16; XCD grid; Q pre-scaled; masked K/V rows zeroed) -> flash attn
// (mask-free, unroll-2 pairs, swapped QK^T, static-max softmax, ones-MFMA
// row-sums, tr_b16 V, XCD grid) -> out GEMM (128x128 gload16, fp32 out)

typedef __bf16 bf16_t;
typedef __bf16 bf16x4 __attribute__((ext_vector_type(4)));
typedef __bf16 bf16x8 __attribute__((ext_vector_type(8)));
typedef float f32x4 __attribute__((ext_vector_type(4)));
typedef unsigned int u32x2 __attribute__((ext_vector_type(2)));

typedef const __attribute__((address_space(1))) void* gas_ptr;
typedef __attribute__((address_space(3))) void* las_ptr;

__device__ __forceinline__ void gload16(const void* g, void* lds) {
    // async global->LDS, 16B/lane; LDS dest = wave-uniform base + lane*16
    __builtin_amdgcn_global_load_lds((gas_ptr)g, (las_ptr)lds, 16, 0, 0);
}

// XOR swizzle for 128-B-row tiles: involution, moves 16B blocks, stays in-row
__device__ __forceinline__ int swz(int o) { return o ^ (((o >> 7) & 7) << 4); }

// V staging pre-permutation: 16B chunk c of subtiled LDS [key/4][d/16][4][16]
// comes from global byte offset (key*128 + d*2) of the 64x64 V tile.
__device__ __forceinline__ int gofs(int c) {
    return ((c >> 5) << 9) + (((c >> 1) & 3) << 7) + (((c >> 3) & 3) << 5) + ((c & 1) << 4);
}

#define TRREAD(dst, addr, IMM) \
    asm volatile("ds_read_b64_tr_b16 %0, %1 offset:" #IMM : "=v"(dst) : "v"(addr))

#if __has_builtin(__builtin_amdgcn_exp2f)
#define EXP2F(x) __builtin_amdgcn_exp2f(x)
#else
#define EXP2F(x) exp2f(x)
#endif
#if __has_builtin(__builtin_amdgcn_rcpf)
#define RCPF(x) __builtin_amdgcn_rcpf(x)
#else
#define RCPF(x) (1.0f / (x))
#endif

// ---------------- prep: cvt w4 + mask bits ----------------------------------
__global__ __launch_bounds__(256) void prep_all_kernel(const float* __restrict__ wq,
                                                       const float* __restrict__ wk,
                                                       const float* __restrict__ wv,
                                                       const float* __restrict__ wo,
                                                       const unsigned char* __restrict__ mraw,
                                                       bf16_t* __restrict__ wdst,
                                                       unsigned long long* __restrict__ mbits) {
    const int bidx = blockIdx.x;
    const int tid = threadIdx.x;
    if (bidx < 2048) {
        // fp32 -> bf16, 4 weight matrices (contiguous dst)
        int idx = bidx * 256 + tid;
        int which = idx >> 17;               // 131072 threads per matrix
        int loc = idx & 131071;
        const float* src = which == 0 ? wq : which == 1 ? wk : which == 2 ? wv : wo;
        int e0 = loc * 8;
        const float4* s = (const float4*)(src + e0);
        float4 a = s[0], c = s[1];
        bf16x8 o;
        o[0] = (bf16_t)a.x; o[1] = (bf16_t)a.y; o[2] = (bf16_t)a.z; o[3] = (bf16_t)a.w;
        o[4] = (bf16_t)c.x; o[5] = (bf16_t)c.y; o[6] = (bf16_t)c.z; o[7] = (bf16_t)c.w;
        *(bf16x8*)(wdst + (size_t)which * 1048576 + e0) = o;
    } else {
        // mask -> per-tile 64-bit masks (int32 vs byte-bool hedge)
        __shared__ int s_isbyte;
        if (tid == 0) s_isbyte = 0;
        __syncthreads();
        int any = 0;
        for (int i = tid; i < 4096; i += 256)
            if ((i & 3) && mraw[i]) any = 1;     // nonzero off-aligned byte => byte layout
        if (any) atomicOr(&s_isbyte, 1);
        __syncthreads();
        if (tid < 64) {
            int b = tid >> 5, kt = tid & 31;
            unsigned long long bits = 0;
            if (s_isbyte) {
                for (int j = 0; j < 64; ++j)
                    if (mraw[b * 2048 + kt * 64 + j]) bits |= 1ull << j;
            } else {
                const int* ri = (const int*)mraw;
                for (int j = 0; j < 64; ++j)
                    if (ri[b * 2048 + kt * 64 + j]) bits |= 1ull << j;
            }
            mbits[tid] = bits;
        }
    }
}

// ---------------- QKV GEMM: 128x128, 768 blocks, all-async staging ----------
// A = fp32 input ([T,B,F], z-selected) staged via gload16 into a SWIZZLED
// fp32 LDS tile (pre-swizzled global source, linear dest; each 1KB chunk is
// one 8-row stripe so the swizzle is chunk-local). Fragments are read with
// the same swizzle and converted fp32->bf16 in-register (VALU has slack).
// B = bf16 weights via gload16 (r10 structure). 2 barriers per K-step.
// z==0 (Q) pre-scaled by 0.125*log2(e); z==1/2 (K/V) masked rows zeroed.
__global__ __launch_bounds__(256) void gemm_qkv_kernel(const float* __restrict__ x0,
                                                       const float* __restrict__ x1,
                                                       const float* __restrict__ x2,
                                                       const bf16_t* __restrict__ Bw0,
                                                       const float* __restrict__ b0,
                                                       const float* __restrict__ b1,
                                                       const float* __restrict__ b2,
                                                       const unsigned long long* __restrict__ mbits,
                                                       bf16_t* __restrict__ outb) {
    __shared__ __align__(16) float  AsmF[128 * 32];   // 16 KB, swizzled 128B rows
    __shared__ __align__(16) bf16_t Bsm[128 * 32];    // 8 KB, linear 64B rows
    const int tid = threadIdx.x;
    const int wave = tid >> 6, lane = tid & 63;
    const int g = lane >> 4, lr = lane & 15;

    // XCD-chunked block id: 768 % 8 == 0, chunk = 96 (bijective)
    const int sid = (blockIdx.x & 7) * 96 + (blockIdx.x >> 3);
    const int z = sid >> 8;                  // 256 blocks per z-slice
    const int rem = sid & 255;
    const int m0 = (rem >> 3) * 128, n0 = (rem & 7) * 128;  // consecutive sids share m0

    const float* Xf = z == 0 ? x0 : z == 1 ? x1 : x2;
    const bf16_t* Bw = Bw0 + (size_t)z * 1048576;
    const float* bias = z == 0 ? b0 : z == 1 ? b1 : b2;
    const float qsc = (z == 0) ? 0.18033688f : 1.0f;   // 0.125*log2e
    const int wm = (wave >> 1) * 64, wn = (wave & 1) * 64;
    const int srow = wave * 32 + (lane >> 2);
    const int scol = (lane & 3) * 8;

    // A staging: chunk c dest byte d = wave*4096 + c*1024 + lane*16 (linear);
    // source tile byte o = swz(d): row = o>>7 (within this chunk's 8-row
    // stripe), f32 col = (o&127)/4. Global row r=(b,t): f32 idx (t*2+b)*1024.
    int arow[4], acol[4];
    #pragma unroll
    for (int c = 0; c < 4; ++c) {
        int d = wave * 4096 + c * 1024 + lane * 16;
        int o = swz(d);
        int r = m0 + (o >> 7);
        arow[c] = (r & 2047) * 2 + (r >> 11);
        acol[c] = (o & 127) >> 2;
    }

    f32x4 acc[4][4] = {};

    for (int k0 = 0; k0 < 1024; k0 += 32) {
        __syncthreads();   // B1: prev iteration's LDS reads done
        #pragma unroll
        for (int c = 0; c < 4; ++c)
            gload16(Xf + (size_t)arow[c] * 1024 + k0 + acol[c],
                    (char*)AsmF + wave * 4096 + c * 1024);
        gload16(Bw + (size_t)(n0 + srow) * 1024 + k0 + scol,      (char*)Bsm + wave * 2048);
        gload16(Bw + (size_t)(n0 + srow + 16) * 1024 + k0 + scol, (char*)Bsm + wave * 2048 + 1024);
        __syncthreads();   // B2: A+B staged (vmcnt drain)

        bf16x8 af[4], bfr[4];
        #pragma unroll
        for (int mi = 0; mi < 4; ++mi) {
            const int row = wm + mi * 16 + lr;
            const int base = row * 128 + g * 32;
            const int sw = (row & 7) << 4;
            float4 lo = *(const float4*)((const char*)AsmF + (base ^ sw));
            float4 hi = *(const float4*)((const char*)AsmF + ((base + 16) ^ sw));
            af[mi][0] = (bf16_t)lo.x; af[mi][1] = (bf16_t)lo.y;
            af[mi][2] = (bf16_t)lo.z; af[mi][3] = (bf16_t)lo.w;
            af[mi][4] = (bf16_t)hi.x; af[mi][5] = (bf16_t)hi.y;
            af[mi][6] = (bf16_t)hi.z; af[mi][7] = (bf16_t)hi.w;
        }
        #pragma unroll
        for (int ni = 0; ni < 4; ++ni)
            bfr[ni] = *(const bf16x8*)(Bsm + (wn + ni * 16 + lr) * 32 + g * 8);
        #pragma unroll
        for (int mi = 0; mi < 4; ++mi)
            #pragma unroll
            for (int ni = 0; ni < 4; ++ni)
                acc[mi][ni] = __builtin_amdgcn_mfma_f32_16x16x32_bf16(af[mi], bfr[ni], acc[mi][ni], 0, 0, 0);
    }

    #pragma unroll
    for (int mi = 0; mi < 4; ++mi) {
        #pragma unroll
        for (int ni = 0; ni < 4; ++ni) {
            int n = n0 + wn + ni * 16 + lr;
            float bs = bias[n];
            #pragma unroll
            for (int i = 0; i < 4; ++i) {
                int m = m0 + wm + mi * 16 + 4 * g + i;
                float v = (acc[mi][ni][i] + bs) * qsc;
                int b = m >> 11, t = m & 2047;
                if (z != 0) {                // zero masked key rows for K/V
                    const bool mk = (mbits[b * 32 + (t >> 6)] >> (t & 63)) & 1;
                    if (mk) v = 0.f;
                }
                int hh = n >> 6, dk = n & 63;
                outb[(size_t)z * 4194304 + ((size_t)(b * 16 + hh) * 2048 + t) * 64 + dk] = (bf16_t)v;
            }
        }
    }
}

// ---------------- out GEMM: 128x128, 256 blocks ------------------------------
__global__ __launch_bounds__(256) void gemm_out_kernel(const bf16_t* __restrict__ Ab,
                                                       const bf16_t* __restrict__ Bw,
                                                       const float* __restrict__ bias,
                                                       float* __restrict__ outf) {
    __shared__ __align__(16) bf16_t Asm[128 * 32];
    __shared__ __align__(16) bf16_t Bsm[128 * 32];
    const int tid = threadIdx.x;
    const int wave = tid >> 6, lane = tid & 63;
    const int g = lane >> 4, lr = lane & 15;

    const int sid = (blockIdx.x & 7) * 32 + (blockIdx.x >> 3);   // 256 % 8 == 0
    const int m0 = (sid >> 3) * 128, n0 = (sid & 7) * 128;
    const int wm = (wave >> 1) * 64, wn = (wave & 1) * 64;
    const int srow = wave * 32 + (lane >> 2);
    const int scol = (lane & 3) * 8;
    const int r0 = m0 + srow, r1 = r0 + 16;

    f32x4 acc[4][4] = {};

    for (int k0 = 0; k0 < 1024; k0 += 32) {
        __syncthreads();
        gload16(Ab + (size_t)r0 * 1024 + k0 + scol,               (char*)Asm + wave * 2048);
        gload16(Ab + (size_t)r1 * 1024 + k0 + scol,               (char*)Asm + wave * 2048 + 1024);
        gload16(Bw + (size_t)(n0 + srow) * 1024 + k0 + scol,      (char*)Bsm + wave * 2048);
        gload16(Bw + (size_t)(n0 + srow + 16) * 1024 + k0 + scol, (char*)Bsm + wave * 2048 + 1024);
        __syncthreads();

        bf16x8 af[4], bfr[4];
        #pragma unroll
        for (int mi = 0; mi < 4; ++mi)
            af[mi] = *(const bf16x8*)(Asm + (wm + mi * 16 + lr) * 32 + g * 8);
        #pragma unroll
        for (int ni = 0; ni < 4; ++ni)
            bfr[ni] = *(const bf16x8*)(Bsm + (wn + ni * 16 + lr) * 32 + g * 8);
        #pragma unroll
        for (int mi = 0; mi < 4; ++mi)
            #pragma unroll
            for (int ni = 0; ni < 4; ++ni)
                acc[mi][ni] = __builtin_amdgcn_mfma_f32_16x16x32_bf16(af[mi], bfr[ni], acc[mi][ni], 0, 0, 0);
    }

    #pragma unroll
    for (int mi = 0; mi < 4; ++mi) {
        #pragma unroll
        for (int ni = 0; ni < 4; ++ni) {
            int n = n0 + wn + ni * 16 + lr;
            float bs = bias[n];
            #pragma unroll
            for (int i = 0; i < 4; ++i) {
                int m = m0 + wm + mi * 16 + 4 * g + i;
                int b = m >> 11, t = m & 2047;
                outf[(size_t)t * 2048 + b * 1024 + n] = acc[mi][ni][i] + bs;
            }
        }
    }
}

// ---------------- flash attention (unchanged) -------------------------------
// 1-D grid 512, XCD-chunked. 4 waves; wave owns 32 q-rows (2 strips of 16).
// MASK-FREE inner loop: masked keys have K-row = 0 (score 0 -> p = 1) and
// V-row = 0 (no PV contribution); denominator = sacc - popcount(mask[b]).
__global__ __launch_bounds__(256, 2) void attn_kernel(const bf16_t* __restrict__ qh,
                                                      const bf16_t* __restrict__ kh,
                                                      const bf16_t* __restrict__ vh,
                                                      const unsigned long long* __restrict__ mbits,
                                                      bf16_t* __restrict__ ctx) {
    __shared__ __align__(16) bf16_t Ks[2][2][64 * 64];  // [pair-parity][tile] swizzled K
    __shared__ __align__(16) bf16_t Vs[2][2][64 * 64];  // [pair-parity][tile] subtiled V

    const int tid = threadIdx.x;
    const int wave = tid >> 6, lane = tid & 63;
    const int g = lane >> 4, lr = lane & 15;
    const int bid = blockIdx.x;
    const int sid = (bid & 7) * 64 + (bid >> 3);       // XCD-chunked (512 % 8 == 0)
    const int bh = sid >> 4, qc = sid & 15;
    const int b = bh >> 4, h = bh & 15;
    const int q0 = qc * 128;
    const bf16_t* Qg = qh + ((size_t)bh * 2048 + q0) * 64;
    const bf16_t* Kg = kh + (size_t)bh * 2048 * 64;
    const bf16_t* Vg = vh + (size_t)bh * 2048 * 64;
    const unsigned long long* mbp = mbits + b * 32;

    const int dstw = wave * 2048;            // wave's 2KB staging chunk (byte offset)
    const int dl = dstw + lane * 16;
    const int wq0 = wave * 32;
    const int vs0 = gofs(wave * 128 + lane);        // V source pre-permutation (bytes)
    const int vs1 = gofs(wave * 128 + 64 + lane);

    // stage Q tile (128 rows = 16 KB) through Ks[0]; Q pre-scaled by 0.125*log2e
    #pragma unroll
    for (int c = 0; c < 4; ++c)
        gload16((const char*)Qg + swz(wave * 4096 + c * 1024 + lane * 16),
                (char*)Ks[0] + wave * 4096 + c * 1024);
    __syncthreads();
    bf16x8 qf[2][2];
    #pragma unroll
    for (int s = 0; s < 2; ++s) {
        qf[s][0] = *(const bf16x8*)((const char*)Ks[0] + swz((wq0 + s * 16 + lr) * 128 + g * 16));
        qf[s][1] = *(const bf16x8*)((const char*)Ks[0] + swz((wq0 + s * 16 + lr) * 128 + 64 + g * 16));
    }
    __syncthreads();   // all waves done reading Q before staging overwrites Ks[0]

    // prologue: stage pair 0 (tiles 0,1)
    #pragma unroll
    for (int u = 0; u < 2; ++u) {
        const char* Kt = (const char*)(Kg + u * 4096);
        const char* Vt = (const char*)(Vg + u * 4096);
        gload16(Kt + swz(dl),        (char*)Ks[0][u] + dstw);
        gload16(Kt + swz(dl + 1024), (char*)Ks[0][u] + dstw + 1024);
        gload16(Vt + vs0,            (char*)Vs[0][u] + dstw);
        gload16(Vt + vs1,            (char*)Vs[0][u] + dstw + 1024);
    }

    // all-ones A fragment for row-sum MFMA
    bf16x8 ones;
    #pragma unroll
    for (int j = 0; j < 8; ++j) ones[j] = (bf16_t)1.0f;

    f32x4 cacc[2][4] = {};
    f32x4 sacc[2] = {};                      // row-sum accumulators (all regs equal)
    const unsigned vbase = (unsigned)(unsigned long long)(las_ptr)&Vs[0][0][0] + g * 512 + lr * 8;

    for (int m = 0; m < 16; ++m) {
        const int par = m & 1;
        __syncthreads();   // drains vmcnt: pair m staged; pair m-1 reads done

        // prefetch pair m+1 into the other parity (in flight across compute)
        if (m < 15) {
            #pragma unroll
            for (int u = 0; u < 2; ++u) {
                const char* Kn = (const char*)(Kg + (2 * m + 2 + u) * 4096);
                const char* Vn = (const char*)(Vg + (2 * m + 2 + u) * 4096);
                gload16(Kn + swz(dl),        (char*)Ks[par ^ 1][u] + dstw);
                gload16(Kn + swz(dl + 1024), (char*)Ks[par ^ 1][u] + dstw + 1024);
                gload16(Vn + vs0,            (char*)Vs[par ^ 1][u] + dstw);
                gload16(Vn + vs1,            (char*)Vs[par ^ 1][u] + dstw + 1024);
            }
        }

        // ---- QK^T for BOTH tiles (independent chains; s2[u] live together)
        f32x4 s2[2][2][4];                   // [tile][strip][st]
        __builtin_amdgcn_s_setprio(1);
        #pragma unroll
        for (int u = 0; u < 2; ++u) {
            const char* Kc = (const char*)Ks[par][u];
            #pragma unroll
            for (int st = 0; st < 4; ++st) {
                bf16x8 kf0 = *(const bf16x8*)(Kc + swz((st * 16 + lr) * 128 + g * 16));
                bf16x8 kf1 = *(const bf16x8*)(Kc + swz((st * 16 + lr) * 128 + 64 + g * 16));
                #pragma unroll
                for (int s = 0; s < 2; ++s) {
                    f32x4 zz = {};
                    zz = __builtin_amdgcn_mfma_f32_16x16x32_bf16(kf0, qf[s][0], zz, 0, 0, 0);
                    zz = __builtin_amdgcn_mfma_f32_16x16x32_bf16(kf1, qf[s][1], zz, 0, 0, 0);
                    s2[u][s][st] = zz;
                }
            }
        }
        __builtin_amdgcn_s_setprio(0);

        // ---- softmax (mask-free: p = exp2(s)) + pack + PV per tile;
        // tile-1's softmax overlaps tile-0's PV MFMAs
        #pragma unroll
        for (int u = 0; u < 2; ++u) {
            #pragma unroll
            for (int st = 0; st < 4; ++st) {
                #pragma unroll
                for (int i = 0; i < 4; ++i) {
                    s2[u][0][st][i] = EXP2F(s2[u][0][st][i]);
                    s2[u][1][st][i] = EXP2F(s2[u][1][st][i]);
                }
            }
            // pack P^T B-fragments: slot j -> key 32kk + 16(j>>2) + 4g + (j&3)
            bf16x8 pb[2][2];
            #pragma unroll
            for (int s = 0; s < 2; ++s)
                #pragma unroll
                for (int kk = 0; kk < 2; ++kk)
                    #pragma unroll
                    for (int j = 0; j < 8; ++j)
                        pb[s][kk][j] = (bf16_t)s2[u][s][2 * kk + (j >> 2)][j & 3];

            // PV: A = V^T fragments via hardware transpose read (16 x b64_tr_b16)
            const unsigned vb = vbase + (unsigned)par * 16384u + (unsigned)u * 8192u;
            u32x2 t[2][2][4];
            TRREAD(t[0][0][0], vb, 0);    TRREAD(t[0][0][1], vb, 128);
            TRREAD(t[0][0][2], vb, 256);  TRREAD(t[0][0][3], vb, 384);
            TRREAD(t[0][1][0], vb, 2048); TRREAD(t[0][1][1], vb, 2176);
            TRREAD(t[0][1][2], vb, 2304); TRREAD(t[0][1][3], vb, 2432);
            TRREAD(t[1][0][0], vb, 4096); TRREAD(t[1][0][1], vb, 4224);
            TRREAD(t[1][0][2], vb, 4352); TRREAD(t[1][0][3], vb, 4480);
            TRREAD(t[1][1][0], vb, 6144); TRREAD(t[1][1][1], vb, 6272);
            TRREAD(t[1][1][2], vb, 6400); TRREAD(t[1][1][3], vb, 6528);
            asm volatile("s_waitcnt lgkmcnt(0)" ::: "memory");
            __builtin_amdgcn_sched_barrier(0);   // rule 18: keep MFMAs after the wait
            __builtin_amdgcn_s_setprio(1);
            #pragma unroll
            for (int kk = 0; kk < 2; ++kk) {
                // row-sum MFMA: D[row][q] = sum_k P^T[k][q] (one per strip per kk)
                sacc[0] = __builtin_amdgcn_mfma_f32_16x16x32_bf16(ones, pb[0][kk], sacc[0], 0, 0, 0);
                sacc[1] = __builtin_amdgcn_mfma_f32_16x16x32_bf16(ones, pb[1][kk], sacc[1], 0, 0, 0);
                #pragma unroll
                for (int ni = 0; ni < 4; ++ni) {
                    union { u32x2 q[2]; bf16x8 v8; } uu;
                    uu.q[0] = t[kk][0][ni];
                    uu.q[1] = t[kk][1][ni];
                    #pragma unroll
                    for (int s = 0; s < 2; ++s)
                        cacc[s][ni] = __builtin_amdgcn_mfma_f32_16x16x32_bf16(uu.v8, pb[s][kk], cacc[s][ni], 0, 0, 0);
                }
            }
            __builtin_amdgcn_s_setprio(0);
        }
    }

    // epilogue: denominator = sacc - nmasked (masked keys contribute exactly
    // 1.0 each: K-row zeroed -> s=0 -> p=1; V-row zeroed -> no PV effect)
    float nm = 0.f;
    #pragma unroll
    for (int i = 0; i < 32; ++i)
        nm += (float)__popcll(mbp[i]);
    #pragma unroll
    for (int s = 0; s < 2; ++s) {
        const float rl = RCPF(sacc[s][0] - nm);
        const int trow = q0 + wq0 + s * 16 + lr;
        #pragma unroll
        for (int ni = 0; ni < 4; ++ni) {
            bf16x4 o;
            #pragma unroll
            for (int i = 0; i < 4; ++i)
                o[i] = (bf16_t)(cacc[s][ni][i] * rl);
            *(bf16x4*)(ctx + ((size_t)b * 2048 + trow) * 1024 + h * 64 + ni * 16 + 4 * g) = o;
        }
    }
}

// ---------------- launch ----------------------------------------------------
extern "C" void kernel_launch(void* const* d_in, const int* in_sizes, int n_in,
                              void* d_out, int out_size, void* d_ws, size_t ws_size,
                              hipStream_t stream) {
    const float* query = (const float*)d_in[0];
    const float* key_  = (const float*)d_in[1];
    const float* value = (const float*)d_in[2];
    const unsigned char* kpm_raw = (const unsigned char*)d_in[3];
    const float* Wq = (const float*)d_in[4];
    const float* bq = (const float*)d_in[5];
    const float* Wk = (const float*)d_in[6];
    const float* bk = (const float*)d_in[7];
    const float* Wv = (const float*)d_in[8];
    const float* bv = (const float*)d_in[9];
    const float* Wo = (const float*)d_in[10];
    const float* bo = (const float*)d_in[11];
    float* out = (float*)d_out;

    char* ws = (char*)d_ws;
    size_t off = 0;
    auto alloc = [&](size_t bytes) {
        char* p = ws + off;
        off += (bytes + 255) & ~(size_t)255;
        return p;
    };
    const size_t SZ_X = (size_t)4096 * 1024 * sizeof(bf16_t);  // 8 MB
    const size_t SZ_W = (size_t)1024 * 1024 * sizeof(bf16_t);  // 2 MB
    bf16_t* wqb = (bf16_t*)alloc(SZ_W);   // wqb..wob contiguous (z-indexed)
    bf16_t* wkb = (bf16_t*)alloc(SZ_W);
    bf16_t* wvb = (bf16_t*)alloc(SZ_W);
    bf16_t* wob = (bf16_t*)alloc(SZ_W);
    bf16_t* qhB = (bf16_t*)alloc(SZ_X);   // qhB,khB,vhB contiguous (z-indexed)
    bf16_t* khB = (bf16_t*)alloc(SZ_X);
    bf16_t* vhB = (bf16_t*)alloc(SZ_X);
    bf16_t* ctxB = (bf16_t*)alloc(SZ_X);
    unsigned long long* mbits = (unsigned long long*)alloc(64 * sizeof(unsigned long long));
    (void)wkb; (void)wvb;

    // prep: 2048 (w4 cvt) + 1 (mask) blocks
    prep_all_kernel<<<2049, 256, 0, stream>>>(Wq, Wk, Wv, Wo, kpm_raw, wqb, mbits);

    // QKV projections: fp32 A via swizzled gload16; 768 blocks XCD-chunked
    gemm_qkv_kernel<<<768, 256, 0, stream>>>(query, key_, value, wqb,
                                             bq, bk, bv, mbits, qhB);

    attn_kernel<<<512, 256, 0, stream>>>(qhB, khB, vhB, mbits, ctxB);

    // out projection: 128x128, 256 blocks
    gemm_out_kernel<<<256, 256, 0, stream>>>(ctxB, wob, bo, out);
}

// Round 17
// 122.491 us; speedup vs baseline: 1.2108x; 1.0438x over previous
//
#include <hip/hip_runtime.h>
#include <hip/hip_bf16.h>
#include <stdint.h>

// ESPNET MultiHeadedAttention: T=2048 B=2 F=1024 H=16 DK=64
// prep(w-cvt+mask) -> QKV proj GEMM (r13 fused fp32-A reg-prefetch + NEW:
// 4-buffer B with raw barriers; B gloads prefetched 2 K-steps ahead and never
// force-drained -> latency covered by 2 compute phases; 40KB LDS = 4 blk/CU)
// -> flash attn (mask-free, unroll-2, swapped QK^T, static-max softmax,
// ones-MFMA row-sums, tr_b16 V, XCD grid) -> out GEMM (128x128 gload16)

typedef __bf16 bf16_t;
typedef __bf16 bf16x4 __attribute__((ext_vector_type(4)));
typedef __bf16 bf16x8 __attribute__((ext_vector_type(8)));
typedef float f32x4 __attribute__((ext_vector_type(4)));
typedef unsigned int u32x2 __attribute__((ext_vector_type(2)));

typedef const __attribute__((address_space(1))) void* gas_ptr;
typedef __attribute__((address_space(3))) void* las_ptr;

__device__ __forceinline__ void gload16(const void* g, void* lds) {
    // async global->LDS, 16B/lane; LDS dest = wave-uniform base + lane*16
    __builtin_amdgcn_global_load_lds((gas_ptr)g, (las_ptr)lds, 16, 0, 0);
}

// XOR swizzle for 128-B-row tiles: involution, moves 16B blocks, stays in-row
__device__ __forceinline__ int swz(int o) { return o ^ (((o >> 7) & 7) << 4); }

// V staging pre-permutation: 16B chunk c of subtiled LDS [key/4][d/16][4][16]
// comes from global byte offset (key*128 + d*2) of the 64x64 V tile.
__device__ __forceinline__ int gofs(int c) {
    return ((c >> 5) << 9) + (((c >> 1) & 3) << 7) + (((c >> 3) & 3) << 5) + ((c & 1) << 4);
}

#define TRREAD(dst, addr, IMM) \
    asm volatile("ds_read_b64_tr_b16 %0, %1 offset:" #IMM : "=v"(dst) : "v"(addr))

#if __has_builtin(__builtin_amdgcn_exp2f)
#define EXP2F(x) __builtin_amdgcn_exp2f(x)
#else
#define EXP2F(x) exp2f(x)
#endif
#if __has_builtin(__builtin_amdgcn_rcpf)
#define RCPF(x) __builtin_amdgcn_rcpf(x)
#else
#define RCPF(x) (1.0f / (x))
#endif

// ---------------- prep: cvt w4 + mask bits ----------------------------------
__global__ __launch_bounds__(256) void prep_all_kernel(const float* __restrict__ wq,
                                                       const float* __restrict__ wk,
                                                       const float* __restrict__ wv,
                                                       const float* __restrict__ wo,
                                                       const unsigned char* __restrict__ mraw,
                                                       bf16_t* __restrict__ wdst,
                                                       unsigned long long* __restrict__ mbits) {
    const int bidx = blockIdx.x;
    const int tid = threadIdx.x;
    if (bidx < 2048) {
        // fp32 -> bf16, 4 weight matrices (contiguous dst)
        int idx = bidx * 256 + tid;
        int which = idx >> 17;               // 131072 threads per matrix
        int loc = idx & 131071;
        const float* src = which == 0 ? wq : which == 1 ? wk : which == 2 ? wv : wo;
        int e0 = loc * 8;
        const float4* s = (const float4*)(src + e0);
        float4 a = s[0], c = s[1];
        bf16x8 o;
        o[0] = (bf16_t)a.x; o[1] = (bf16_t)a.y; o[2] = (bf16_t)a.z; o[3] = (bf16_t)a.w;
        o[4] = (bf16_t)c.x; o[5] = (bf16_t)c.y; o[6] = (bf16_t)c.z; o[7] = (bf16_t)c.w;
        *(bf16x8*)(wdst + (size_t)which * 1048576 + e0) = o;
    } else {
        // mask -> per-tile 64-bit masks (int32 vs byte-bool hedge)
        __shared__ int s_isbyte;
        if (tid == 0) s_isbyte = 0;
        __syncthreads();
        int any = 0;
        for (int i = tid; i < 4096; i += 256)
            if ((i & 3) && mraw[i]) any = 1;     // nonzero off-aligned byte => byte layout
        if (any) atomicOr(&s_isbyte, 1);
        __syncthreads();
        if (tid < 64) {
            int b = tid >> 5, kt = tid & 31;
            unsigned long long bits = 0;
            if (s_isbyte) {
                for (int j = 0; j < 64; ++j)
                    if (mraw[b * 2048 + kt * 64 + j]) bits |= 1ull << j;
            } else {
                const int* ri = (const int*)mraw;
                for (int j = 0; j < 64; ++j)
                    if (ri[b * 2048 + kt * 64 + j]) bits |= 1ull << j;
            }
            mbits[tid] = bits;
        }
    }
}

// ---------------- QKV GEMM: fused fp32-A, 4-buffer B, raw barriers ----------
// Per iteration it: [s_barrier] -> cvt+ds_write A(it) (compiler's vmcnt wait
// for the A regs transitively guarantees B(it), issued 2 iters earlier and
// OLDER in the vmcnt queue, has landed) -> issue A(it+1) reg loads, then
// B(it+2) gloads (A-first order keeps B newer -> never force-drained) ->
// [lgkmcnt(0); s_barrier] -> fragment reads + MFMA on Asm / Bsm[it&3].
// z==0 (Q) pre-scaled by 0.125*log2(e); z==1/2 (K/V) masked rows zeroed.
__global__ __launch_bounds__(256) void gemm_qkv_kernel(const float* __restrict__ x0,
                                                       const float* __restrict__ x1,
                                                       const float* __restrict__ x2,
                                                       const bf16_t* __restrict__ Bw0,
                                                       const float* __restrict__ b0,
                                                       const float* __restrict__ b1,
                                                       const float* __restrict__ b2,
                                                       const unsigned long long* __restrict__ mbits,
                                                       bf16_t* __restrict__ outb) {
    __shared__ __align__(16) bf16_t Asm[128 * 32];      // 8 KB single buffer
    __shared__ __align__(16) bf16_t Bsm[4][128 * 32];   // 4 x 8 KB
    const int tid = threadIdx.x;
    const int wave = tid >> 6, lane = tid & 63;
    const int g = lane >> 4, lr = lane & 15;

    // XCD-chunked block id: 768 % 8 == 0, chunk = 96 (bijective)
    const int sid = (blockIdx.x & 7) * 96 + (blockIdx.x >> 3);
    const int z = sid >> 8;                  // 256 blocks per z-slice
    const int rem = sid & 255;
    const int m0 = (rem >> 3) * 128, n0 = (rem & 7) * 128;  // consecutive sids share m0

    const float* Xf = z == 0 ? x0 : z == 1 ? x1 : x2;
    const bf16_t* Bw = Bw0 + (size_t)z * 1048576;
    const float* bias = z == 0 ? b0 : z == 1 ? b1 : b2;
    const float qsc = (z == 0) ? 0.18033688f : 1.0f;   // 0.125*log2e
    const int wm = (wave >> 1) * 64, wn = (wave & 1) * 64;
    const int srow = wave * 32 + (lane >> 2);
    const int scol = (lane & 3) * 8;

    // fp32 A source: row r=(b,t) of [T,B,F] -> f32 idx (t*2+b)*1024
    const int r0 = m0 + srow, r1 = r0 + 16;
    const size_t fb0 = (size_t)((r0 & 2047) * 2 + (r0 >> 11)) * 1024 + scol;
    const size_t fb1 = (size_t)((r1 & 2047) * 2 + (r1 >> 11)) * 1024 + scol;
    // B source rows (bf16)
    const bf16_t* gB0 = Bw + (size_t)(n0 + srow) * 1024 + scol;
    const bf16_t* gB1 = Bw + (size_t)(n0 + srow + 16) * 1024 + scol;
    // LDS dest bytes
    char* dA0 = (char*)Asm + wave * 2048 + lane * 16;
    char* dA1 = dA0 + 1024;

    f32x4 acc[4][4] = {};
    float4 a00, a01, a10, a11;               // prefetched A registers

    // prologue (issue order matters): B(0), A(0), B(1)
    gload16(gB0,      (char*)Bsm[0] + wave * 2048);
    gload16(gB1,      (char*)Bsm[0] + wave * 2048 + 1024);
    a00 = *(const float4*)(Xf + fb0);
    a01 = *(const float4*)(Xf + fb0 + 4);
    a10 = *(const float4*)(Xf + fb1);
    a11 = *(const float4*)(Xf + fb1 + 4);
    gload16(gB0 + 32, (char*)Bsm[1] + wave * 2048);
    gload16(gB1 + 32, (char*)Bsm[1] + wave * 2048 + 1024);

    for (int it = 0; it < 32; ++it) {
        const int k0 = it * 32;
        __builtin_amdgcn_s_barrier();        // B1: protects Asm overwrite
        __builtin_amdgcn_sched_barrier(0);
        {
            // cvt + ds_write A(it); compiler waits vmcnt for a-regs here,
            // which (in-order queue) also guarantees B(it) has landed.
            bf16x8 w0, w1;
            w0[0] = (bf16_t)a00.x; w0[1] = (bf16_t)a00.y; w0[2] = (bf16_t)a00.z; w0[3] = (bf16_t)a00.w;
            w0[4] = (bf16_t)a01.x; w0[5] = (bf16_t)a01.y; w0[6] = (bf16_t)a01.z; w0[7] = (bf16_t)a01.w;
            w1[0] = (bf16_t)a10.x; w1[1] = (bf16_t)a10.y; w1[2] = (bf16_t)a10.z; w1[3] = (bf16_t)a10.w;
            w1[4] = (bf16_t)a11.x; w1[5] = (bf16_t)a11.y; w1[6] = (bf16_t)a11.z; w1[7] = (bf16_t)a11.w;
            *(bf16x8*)dA0 = w0;
            *(bf16x8*)dA1 = w1;
        }
        // issue A(it+1) FIRST, then B(it+2): keeps B newest in the vmcnt
        // queue so the next iteration's A-wait leaves it in flight.
        if (it < 31) {
            a00 = *(const float4*)(Xf + fb0 + k0 + 32);
            a01 = *(const float4*)(Xf + fb0 + k0 + 36);
            a10 = *(const float4*)(Xf + fb1 + k0 + 32);
            a11 = *(const float4*)(Xf + fb1 + k0 + 36);
        }
        if (it < 30) {
            gload16(gB0 + k0 + 64, (char*)Bsm[(it + 2) & 3] + wave * 2048);
            gload16(gB1 + k0 + 64, (char*)Bsm[(it + 2) & 3] + wave * 2048 + 1024);
        }
        asm volatile("s_waitcnt lgkmcnt(0)" ::: "memory");   // ds_writes visible
        __builtin_amdgcn_s_barrier();        // B2 (no vmcnt drain!)
        __builtin_amdgcn_sched_barrier(0);

        const bf16_t* Bc = Bsm[it & 3];
        bf16x8 af[4], bfr[4];
        #pragma unroll
        for (int mi = 0; mi < 4; ++mi)
            af[mi] = *(const bf16x8*)(Asm + (wm + mi * 16 + lr) * 32 + g * 8);
        #pragma unroll
        for (int ni = 0; ni < 4; ++ni)
            bfr[ni] = *(const bf16x8*)(Bc + (wn + ni * 16 + lr) * 32 + g * 8);
        #pragma unroll
        for (int mi = 0; mi < 4; ++mi)
            #pragma unroll
            for (int ni = 0; ni < 4; ++ni)
                acc[mi][ni] = __builtin_amdgcn_mfma_f32_16x16x32_bf16(af[mi], bfr[ni], acc[mi][ni], 0, 0, 0);
    }

    #pragma unroll
    for (int mi = 0; mi < 4; ++mi) {
        #pragma unroll
        for (int ni = 0; ni < 4; ++ni) {
            int n = n0 + wn + ni * 16 + lr;
            float bs = bias[n];
            #pragma unroll
            for (int i = 0; i < 4; ++i) {
                int m = m0 + wm + mi * 16 + 4 * g + i;
                float v = (acc[mi][ni][i] + bs) * qsc;
                int b = m >> 11, t = m & 2047;
                if (z != 0) {                // zero masked key rows for K/V
                    const bool mk = (mbits[b * 32 + (t >> 6)] >> (t & 63)) & 1;
                    if (mk) v = 0.f;
                }
                int hh = n >> 6, dk = n & 63;
                outb[(size_t)z * 4194304 + ((size_t)(b * 16 + hh) * 2048 + t) * 64 + dk] = (bf16_t)v;
            }
        }
    }
}

// ---------------- out GEMM: 128x128, 256 blocks ------------------------------
__global__ __launch_bounds__(256) void gemm_out_kernel(const bf16_t* __restrict__ Ab,
                                                       const bf16_t* __restrict__ Bw,
                                                       const float* __restrict__ bias,
                                                       float* __restrict__ outf) {
    __shared__ __align__(16) bf16_t Asm[128 * 32];
    __shared__ __align__(16) bf16_t Bsm[128 * 32];
    const int tid = threadIdx.x;
    const int wave = tid >> 6, lane = tid & 63;
    const int g = lane >> 4, lr = lane & 15;

    const int sid = (blockIdx.x & 7) * 32 + (blockIdx.x >> 3);   // 256 % 8 == 0
    const int m0 = (sid >> 3) * 128, n0 = (sid & 7) * 128;
    const int wm = (wave >> 1) * 64, wn = (wave & 1) * 64;
    const int srow = wave * 32 + (lane >> 2);
    const int scol = (lane & 3) * 8;
    const int r0 = m0 + srow, r1 = r0 + 16;

    f32x4 acc[4][4] = {};

    for (int k0 = 0; k0 < 1024; k0 += 32) {
        __syncthreads();
        gload16(Ab + (size_t)r0 * 1024 + k0 + scol,               (char*)Asm + wave * 2048);
        gload16(Ab + (size_t)r1 * 1024 + k0 + scol,               (char*)Asm + wave * 2048 + 1024);
        gload16(Bw + (size_t)(n0 + srow) * 1024 + k0 + scol,      (char*)Bsm + wave * 2048);
        gload16(Bw + (size_t)(n0 + srow + 16) * 1024 + k0 + scol, (char*)Bsm + wave * 2048 + 1024);
        __syncthreads();

        bf16x8 af[4], bfr[4];
        #pragma unroll
        for (int mi = 0; mi < 4; ++mi)
            af[mi] = *(const bf16x8*)(Asm + (wm + mi * 16 + lr) * 32 + g * 8);
        #pragma unroll
        for (int ni = 0; ni < 4; ++ni)
            bfr[ni] = *(const bf16x8*)(Bsm + (wn + ni * 16 + lr) * 32 + g * 8);
        #pragma unroll
        for (int mi = 0; mi < 4; ++mi)
            #pragma unroll
            for (int ni = 0; ni < 4; ++ni)
                acc[mi][ni] = __builtin_amdgcn_mfma_f32_16x16x32_bf16(af[mi], bfr[ni], acc[mi][ni], 0, 0, 0);
    }

    #pragma unroll
    for (int mi = 0; mi < 4; ++mi) {
        #pragma unroll
        for (int ni = 0; ni < 4; ++ni) {
            int n = n0 + wn + ni * 16 + lr;
            float bs = bias[n];
            #pragma unroll
            for (int i = 0; i < 4; ++i) {
                int m = m0 + wm + mi * 16 + 4 * g + i;
                int b = m >> 11, t = m & 2047;
                outf[(size_t)t * 2048 + b * 1024 + n] = acc[mi][ni][i] + bs;
            }
        }
    }
}

// ---------------- flash attention (unchanged) -------------------------------
// 1-D grid 512, XCD-chunked. 4 waves; wave owns 32 q-rows (2 strips of 16).
// MASK-FREE inner loop: masked keys have K-row = 0 (score 0 -> p = 1) and
// V-row = 0 (no PV contribution); denominator = sacc - popcount(mask[b]).
__global__ __launch_bounds__(256, 2) void attn_kernel(const bf16_t* __restrict__ qh,
                                                      const bf16_t* __restrict__ kh,
                                                      const bf16_t* __restrict__ vh,
                                                      const unsigned long long* __restrict__ mbits,
                                                      bf16_t* __restrict__ ctx) {
    __shared__ __align__(16) bf16_t Ks[2][2][64 * 64];  // [pair-parity][tile] swizzled K
    __shared__ __align__(16) bf16_t Vs[2][2][64 * 64];  // [pair-parity][tile] subtiled V

    const int tid = threadIdx.x;
    const int wave = tid >> 6, lane = tid & 63;
    const int g = lane >> 4, lr = lane & 15;
    const int bid = blockIdx.x;
    const int sid = (bid & 7) * 64 + (bid >> 3);       // XCD-chunked (512 % 8 == 0)
    const int bh = sid >> 4, qc = sid & 15;
    const int b = bh >> 4, h = bh & 15;
    const int q0 = qc * 128;
    const bf16_t* Qg = qh + ((size_t)bh * 2048 + q0) * 64;
    const bf16_t* Kg = kh + (size_t)bh * 2048 * 64;
    const bf16_t* Vg = vh + (size_t)bh * 2048 * 64;
    const unsigned long long* mbp = mbits + b * 32;

    const int dstw = wave * 2048;            // wave's 2KB staging chunk (byte offset)
    const int dl = dstw + lane * 16;
    const int wq0 = wave * 32;
    const int vs0 = gofs(wave * 128 + lane);        // V source pre-permutation (bytes)
    const int vs1 = gofs(wave * 128 + 64 + lane);

    // stage Q tile (128 rows = 16 KB) through Ks[0]; Q pre-scaled by 0.125*log2e
    #pragma unroll
    for (int c = 0; c < 4; ++c)
        gload16((const char*)Qg + swz(wave * 4096 + c * 1024 + lane * 16),
                (char*)Ks[0] + wave * 4096 + c * 1024);
    __syncthreads();
    bf16x8 qf[2][2];
    #pragma unroll
    for (int s = 0; s < 2; ++s) {
        qf[s][0] = *(const bf16x8*)((const char*)Ks[0] + swz((wq0 + s * 16 + lr) * 128 + g * 16));
        qf[s][1] = *(const bf16x8*)((const char*)Ks[0] + swz((wq0 + s * 16 + lr) * 128 + 64 + g * 16));
    }
    __syncthreads();   // all waves done reading Q before staging overwrites Ks[0]

    // prologue: stage pair 0 (tiles 0,1)
    #pragma unroll
    for (int u = 0; u < 2; ++u) {
        const char* Kt = (const char*)(Kg + u * 4096);
        const char* Vt = (const char*)(Vg + u * 4096);
        gload16(Kt + swz(dl),        (char*)Ks[0][u] + dstw);
        gload16(Kt + swz(dl + 1024), (char*)Ks[0][u] + dstw + 1024);
        gload16(Vt + vs0,            (char*)Vs[0][u] + dstw);
        gload16(Vt + vs1,            (char*)Vs[0][u] + dstw + 1024);
    }

    // all-ones A fragment for row-sum MFMA
    bf16x8 ones;
    #pragma unroll
    for (int j = 0; j < 8; ++j) ones[j] = (bf16_t)1.0f;

    f32x4 cacc[2][4] = {};
    f32x4 sacc[2] = {};                      // row-sum accumulators (all regs equal)
    const unsigned vbase = (unsigned)(unsigned long long)(las_ptr)&Vs[0][0][0] + g * 512 + lr * 8;

    for (int m = 0; m < 16; ++m) {
        const int par = m & 1;
        __syncthreads();   // drains vmcnt: pair m staged; pair m-1 reads done

        // prefetch pair m+1 into the other parity (in flight across compute)
        if (m < 15) {
            #pragma unroll
            for (int u = 0; u < 2; ++u) {
                const char* Kn = (const char*)(Kg + (2 * m + 2 + u) * 4096);
                const char* Vn = (const char*)(Vg + (2 * m + 2 + u) * 4096);
                gload16(Kn + swz(dl),        (char*)Ks[par ^ 1][u] + dstw);
                gload16(Kn + swz(dl + 1024), (char*)Ks[par ^ 1][u] + dstw + 1024);
                gload16(Vn + vs0,            (char*)Vs[par ^ 1][u] + dstw);
                gload16(Vn + vs1,            (char*)Vs[par ^ 1][u] + dstw + 1024);
            }
        }

        // ---- QK^T for BOTH tiles (independent chains; s2[u] live together)
        f32x4 s2[2][2][4];                   // [tile][strip][st]
        __builtin_amdgcn_s_setprio(1);
        #pragma unroll
        for (int u = 0; u < 2; ++u) {
            const char* Kc = (const char*)Ks[par][u];
            #pragma unroll
            for (int st = 0; st < 4; ++st) {
                bf16x8 kf0 = *(const bf16x8*)(Kc + swz((st * 16 + lr) * 128 + g * 16));
                bf16x8 kf1 = *(const bf16x8*)(Kc + swz((st * 16 + lr) * 128 + 64 + g * 16));
                #pragma unroll
                for (int s = 0; s < 2; ++s) {
                    f32x4 zz = {};
                    zz = __builtin_amdgcn_mfma_f32_16x16x32_bf16(kf0, qf[s][0], zz, 0, 0, 0);
                    zz = __builtin_amdgcn_mfma_f32_16x16x32_bf16(kf1, qf[s][1], zz, 0, 0, 0);
                    s2[u][s][st] = zz;
                }
            }
        }
        __builtin_amdgcn_s_setprio(0);

        // ---- softmax (mask-free: p = exp2(s)) + pack + PV per tile;
        // tile-1's softmax overlaps tile-0's PV MFMAs
        #pragma unroll
        for (int u = 0; u < 2; ++u) {
            #pragma unroll
            for (int st = 0; st < 4; ++st) {
                #pragma unroll
                for (int i = 0; i < 4; ++i) {
                    s2[u][0][st][i] = EXP2F(s2[u][0][st][i]);
                    s2[u][1][st][i] = EXP2F(s2[u][1][st][i]);
                }
            }
            // pack P^T B-fragments: slot j -> key 32kk + 16(j>>2) + 4g + (j&3)
            bf16x8 pb[2][2];
            #pragma unroll
            for (int s = 0; s < 2; ++s)
                #pragma unroll
                for (int kk = 0; kk < 2; ++kk)
                    #pragma unroll
                    for (int j = 0; j < 8; ++j)
                        pb[s][kk][j] = (bf16_t)s2[u][s][2 * kk + (j >> 2)][j & 3];

            // PV: A = V^T fragments via hardware transpose read (16 x b64_tr_b16)
            const unsigned vb = vbase + (unsigned)par * 16384u + (unsigned)u * 8192u;
            u32x2 t[2][2][4];
            TRREAD(t[0][0][0], vb, 0);    TRREAD(t[0][0][1], vb, 128);
            TRREAD(t[0][0][2], vb, 256);  TRREAD(t[0][0][3], vb, 384);
            TRREAD(t[0][1][0], vb, 2048); TRREAD(t[0][1][1], vb, 2176);
            TRREAD(t[0][1][2], vb, 2304); TRREAD(t[0][1][3], vb, 2432);
            TRREAD(t[1][0][0], vb, 4096); TRREAD(t[1][0][1], vb, 4224);
            TRREAD(t[1][0][2], vb, 4352); TRREAD(t[1][0][3], vb, 4480);
            TRREAD(t[1][1][0], vb, 6144); TRREAD(t[1][1][1], vb, 6272);
            TRREAD(t[1][1][2], vb, 6400); TRREAD(t[1][1][3], vb, 6528);
            asm volatile("s_waitcnt lgkmcnt(0)" ::: "memory");
            __builtin_amdgcn_sched_barrier(0);   // rule 18: keep MFMAs after the wait
            __builtin_amdgcn_s_setprio(1);
            #pragma unroll
            for (int kk = 0; kk < 2; ++kk) {
                // row-sum MFMA: D[row][q] = sum_k P^T[k][q] (one per strip per kk)
                sacc[0] = __builtin_amdgcn_mfma_f32_16x16x32_bf16(ones, pb[0][kk], sacc[0], 0, 0, 0);
                sacc[1] = __builtin_amdgcn_mfma_f32_16x16x32_bf16(ones, pb[1][kk], sacc[1], 0, 0, 0);
                #pragma unroll
                for (int ni = 0; ni < 4; ++ni) {
                    union { u32x2 q[2]; bf16x8 v8; } uu;
                    uu.q[0] = t[kk][0][ni];
                    uu.q[1] = t[kk][1][ni];
                    #pragma unroll
                    for (int s = 0; s < 2; ++s)
                        cacc[s][ni] = __builtin_amdgcn_mfma_f32_16x16x32_bf16(uu.v8, pb[s][kk], cacc[s][ni], 0, 0, 0);
                }
            }
            __builtin_amdgcn_s_setprio(0);
        }
    }

    // epilogue: denominator = sacc - nmasked (masked keys contribute exactly
    // 1.0 each: K-row zeroed -> s=0 -> p=1; V-row zeroed -> no PV effect)
    float nm = 0.f;
    #pragma unroll
    for (int i = 0; i < 32; ++i)
        nm += (float)__popcll(mbp[i]);
    #pragma unroll
    for (int s = 0; s < 2; ++s) {
        const float rl = RCPF(sacc[s][0] - nm);
        const int trow = q0 + wq0 + s * 16 + lr;
        #pragma unroll
        for (int ni = 0; ni < 4; ++ni) {
            bf16x4 o;
            #pragma unroll
            for (int i = 0; i < 4; ++i)
                o[i] = (bf16_t)(cacc[s][ni][i] * rl);
            *(bf16x4*)(ctx + ((size_t)b * 2048 + trow) * 1024 + h * 64 + ni * 16 + 4 * g) = o;
        }
    }
}

// ---------------- launch ----------------------------------------------------
extern "C" void kernel_launch(void* const* d_in, const int* in_sizes, int n_in,
                              void* d_out, int out_size, void* d_ws, size_t ws_size,
                              hipStream_t stream) {
    const float* query = (const float*)d_in[0];
    const float* key_  = (const float*)d_in[1];
    const float* value = (const float*)d_in[2];
    const unsigned char* kpm_raw = (const unsigned char*)d_in[3];
    const float* Wq = (const float*)d_in[4];
    const float* bq = (const float*)d_in[5];
    const float* Wk = (const float*)d_in[6];
    const float* bk = (const float*)d_in[7];
    const float* Wv = (const float*)d_in[8];
    const float* bv = (const float*)d_in[9];
    const float* Wo = (const float*)d_in[10];
    const float* bo = (const float*)d_in[11];
    float* out = (float*)d_out;

    char* ws = (char*)d_ws;
    size_t off = 0;
    auto alloc = [&](size_t bytes) {
        char* p = ws + off;
        off += (bytes + 255) & ~(size_t)255;
        return p;
    };
    const size_t SZ_X = (size_t)4096 * 1024 * sizeof(bf16_t);  // 8 MB
    const size_t SZ_W = (size_t)1024 * 1024 * sizeof(bf16_t);  // 2 MB
    bf16_t* wqb = (bf16_t*)alloc(SZ_W);   // wqb..wob contiguous (z-indexed)
    bf16_t* wkb = (bf16_t*)alloc(SZ_W);
    bf16_t* wvb = (bf16_t*)alloc(SZ_W);
    bf16_t* wob = (bf16_t*)alloc(SZ_W);
    bf16_t* qhB = (bf16_t*)alloc(SZ_X);   // qhB,khB,vhB contiguous (z-indexed)
    bf16_t* khB = (bf16_t*)alloc(SZ_X);
    bf16_t* vhB = (bf16_t*)alloc(SZ_X);
    bf16_t* ctxB = (bf16_t*)alloc(SZ_X);
    unsigned long long* mbits = (unsigned long long*)alloc(64 * sizeof(unsigned long long));
    (void)wkb; (void)wvb;

    // prep: 2048 (w4 cvt) + 1 (mask) blocks
    prep_all_kernel<<<2049, 256, 0, stream>>>(Wq, Wk, Wv, Wo, kpm_raw, wqb, mbits);

    // QKV projections: fused fp32-A, 4-buffer B; 768 blocks XCD-chunked
    gemm_qkv_kernel<<<768, 256, 0, stream>>>(query, key_, value, wqb,
                                             bq, bk, bv, mbits, qhB);

    attn_kernel<<<512, 256, 0, stream>>>(qhB, khB, vhB, mbits, ctxB);

    // out projection: 128x128, 256 blocks
    gemm_out_kernel<<<256, 256, 0, stream>>>(ctxB, wob, bo, out);
}